// Round 1
// baseline (220.888 us; speedup 1.0000x reference)
//
#include <hip/hip_runtime.h>
#include <math.h>

// Requires ws_size >= 50,339,840 bytes (~48 MiB) of scratch.
#define B_  2
#define T_  2048
#define C_  1024
#define NH_ 16
#define HD_ 64
#define N3_ 3072

typedef float f32x4 __attribute__((ext_vector_type(4)));
typedef short bf16x8 __attribute__((ext_vector_type(8)));
typedef unsigned short u16;

__device__ __forceinline__ u16 f2bf(float x) {
  unsigned int u = __builtin_bit_cast(unsigned int, x);
  u += 0x7FFFu + ((u >> 16) & 1u);
  return (u16)(u >> 16);
}

#define GLD16(g, l) __builtin_amdgcn_global_load_lds( \
    (__attribute__((address_space(1))) void*)(g), \
    (__attribute__((address_space(3))) void*)(l), 16, 0, 0)

// ---------------- converts ----------------
__global__ __launch_bounds__(256) void cvt4_kernel(const float* __restrict__ in,
                                                   u16* __restrict__ out, int n) {
  int i = (blockIdx.x * 256 + threadIdx.x) * 4;
  if (i >= n) return;
  float4 v = *(const float4*)(in + i);
  ushort4 o;
  o.x = f2bf(v.x); o.y = f2bf(v.y); o.z = f2bf(v.z); o.w = f2bf(v.w);
  *(ushort4*)(out + i) = o;
}

// out[c][r] = bf16(in[r][c]); R,Cc multiples of 32
__global__ __launch_bounds__(256) void transpose_cvt_kernel(const float* __restrict__ in,
                                                            u16* __restrict__ out,
                                                            int R, int Cc) {
  __shared__ float tile[32][33];
  int c0 = blockIdx.x * 32, r0 = blockIdx.y * 32;
  int tx = threadIdx.x & 31, ty = threadIdx.x >> 5;
#pragma unroll
  for (int rr = ty; rr < 32; rr += 8)
    tile[rr][tx] = in[(size_t)(r0 + rr) * Cc + c0 + tx];
  __syncthreads();
#pragma unroll
  for (int rr = ty; rr < 32; rr += 8)
    out[(size_t)(c0 + rr) * R + r0 + tx] = f2bf(tile[tx][rr]);
}

__global__ __launch_bounds__(256) void decay_init_kernel(float* __restrict__ decay) {
  int d = blockIdx.x * 256 + threadIdx.x;
  if (d >= T_) return;
  float v = 1.0f;
  if (d >= 15) v = 1.0f - powf((float)(d - 15) * (1.0f / 2032.0f), 0.36787944117144233f);
  decay[d] = v;
}

// ---------------- GEMM: C[M][N] = A[M][K] * Bt[N][K]^T ----------------
// 128x128 tile, 4 waves (2x2 of 64x64), BK=32, global_load_lds w/ XOR-swizzled src.
// MODE 0: store bf16 into qkv split layout [which][b][h][t][d]
// MODE 1: store fp32 row-major
template<int MODE>
__global__ __launch_bounds__(256) void gemm128_kernel(
    const u16* __restrict__ A, const u16* __restrict__ Bt,
    float* __restrict__ Cf, u16* __restrict__ Cq,
    int M, int N, int K)
{
  __shared__ char lds[16384];   // A tile [128][32] @0, Bt tile [128][32] @8192
  const int lane = threadIdx.x & 63;
  const int wave = threadIdx.x >> 6;
  const int m0 = blockIdx.y << 7;
  const int n0 = blockIdx.x << 7;
  const int wm = wave >> 1, wn = wave & 1;

  f32x4 acc[4][4] = {};

  for (int k0 = 0; k0 < K; k0 += 32) {
#pragma unroll
    for (int c = 0; c < 2; ++c) {
      int chunk = wave * 2048 + c * 1024;
      int row = (chunk >> 6) + (lane >> 2);
      int wb = ((lane & 3) << 4) ^ ((row & 3) << 4);   // pre-swizzled source col
      GLD16((const char*)(A  + (size_t)(m0 + row) * K + k0) + wb, lds + chunk);
      GLD16((const char*)(Bt + (size_t)(n0 + row) * K + k0) + wb, lds + 8192 + chunk);
    }
    __syncthreads();
    bf16x8 af[4], bfr[4];
#pragma unroll
    for (int m = 0; m < 4; ++m) {
      int row = wm * 64 + m * 16 + (lane & 15);
      int wb = ((lane >> 4) << 4) ^ ((row & 3) << 4);
      af[m] = *(const bf16x8*)(lds + row * 64 + wb);
    }
#pragma unroll
    for (int n = 0; n < 4; ++n) {
      int row = wn * 64 + n * 16 + (lane & 15);
      int wb = ((lane >> 4) << 4) ^ ((row & 3) << 4);
      bfr[n] = *(const bf16x8*)(lds + 8192 + row * 64 + wb);
    }
#pragma unroll
    for (int m = 0; m < 4; ++m)
#pragma unroll
      for (int n = 0; n < 4; ++n)
        acc[m][n] = __builtin_amdgcn_mfma_f32_16x16x32_bf16(af[m], bfr[n], acc[m][n], 0, 0, 0);
    __syncthreads();
  }

#pragma unroll
  for (int m = 0; m < 4; ++m) {
    int grow0 = m0 + wm * 64 + m * 16 + ((lane >> 4) << 2);
#pragma unroll
    for (int n = 0; n < 4; ++n) {
      int gcol = n0 + wn * 64 + n * 16 + (lane & 15);
      f32x4 v = acc[m][n];
#pragma unroll
      for (int r = 0; r < 4; ++r) {
        int grow = grow0 + r;
        if (MODE == 0) {
          int bb = grow >> 11, tt = grow & 2047;
          int which = gcol >> 10, rem = gcol & 1023;
          int hh = rem >> 6, dd = rem & 63;
          size_t idx = ((((size_t)which * 2 + bb) * 16 + hh) * 2048 + tt) * 64 + dd;
          Cq[idx] = f2bf(v[r]);
        } else {
          Cf[(size_t)grow * N + gcol] = v[r];
        }
      }
    }
  }
}

// ---------------- fused flash attention with post-softmax decay ----------------
// grid: (32 q-tiles, 32 bh); block: 4 waves, each wave owns 16 q-rows.
__global__ __launch_bounds__(256) void attn_kernel(
    const u16* __restrict__ qkvb, const float* __restrict__ decay,
    u16* __restrict__ yb)
{
  __shared__ char klds[8192];       // K tile [64][128B], XOR-swizzled rows
  __shared__ u16 vt[64 * 72];       // V^T [d][key], padded stride 72
  __shared__ u16 plds[64 * 72];     // P   [q][key], padded stride 72

  const int lane = threadIdx.x & 63;
  const int wave = threadIdx.x >> 6;
  const int qt = (int)gridDim.x - 1 - (int)blockIdx.x;   // heavy tiles dispatch first
  const int bh = blockIdx.y;
  const int b = bh >> 4, h = bh & 15;

  const u16* Q  = qkvb + (((size_t)0 * B_ + b) * NH_ + h) * T_ * HD_;
  const u16* Kg = qkvb + (((size_t)1 * B_ + b) * NH_ + h) * T_ * HD_;
  const u16* Vg = qkvb + (((size_t)2 * B_ + b) * NH_ + h) * T_ * HD_;

  const int qrow = qt * 64 + wave * 16 + (lane & 15);
  bf16x8 qa0 = *(const bf16x8*)(Q + (size_t)qrow * HD_ + ((lane >> 4) << 3));
  bf16x8 qa1 = *(const bf16x8*)(Q + (size_t)qrow * HD_ + 32 + ((lane >> 4) << 3));

  f32x4 acc[4] = {};
  float mrow[4], lrow[4];
#pragma unroll
  for (int r = 0; r < 4; ++r) { mrow[r] = -1e30f; lrow[r] = 0.0f; }

  for (int kt = 0; kt <= qt; ++kt) {
    // stage K tile, swizzled source so LDS reads are ~2-way conflict free
#pragma unroll
    for (int c = 0; c < 2; ++c) {
      int chunk = wave * 2048 + c * 1024;
      int row = (chunk >> 7) + (lane >> 3);
      int wb = ((lane & 7) << 4) ^ ((row & 7) << 4);
      GLD16((const char*)(Kg + (size_t)(kt * 64 + row) * HD_) + wb, klds + chunk);
    }
    // stage V^T via registers (scalar transposed writes, 2-way/free)
    {
      int key = threadIdx.x & 63;
      int d0 = (threadIdx.x >> 6) << 4;
      const u16* src = Vg + (size_t)(kt * 64 + key) * HD_ + d0;
      bf16x8 v0 = *(const bf16x8*)(src);
      bf16x8 v1 = *(const bf16x8*)(src + 8);
#pragma unroll
      for (int j = 0; j < 8; ++j) {
        vt[(d0 + j) * 72 + key]     = (u16)v0[j];
        vt[(d0 + 8 + j) * 72 + key] = (u16)v1[j];
      }
    }
    __syncthreads();

    // S = Q K^T * (1/8);  D layout: row=(lane>>4)*4+r (q), col=lane&15 (key)
    f32x4 sf[4];
#pragma unroll
    for (int f = 0; f < 4; ++f) {
      int krow = f * 16 + (lane & 15);
      int base = krow * 128;
      int msk = (krow & 7) << 4;
      bf16x8 b0 = *(const bf16x8*)(klds + base + ((((lane >> 4) << 4)) ^ msk));
      bf16x8 b1 = *(const bf16x8*)(klds + base + ((64 + ((lane >> 4) << 4)) ^ msk));
      f32x4 s = {};
      s = __builtin_amdgcn_mfma_f32_16x16x32_bf16(qa0, b0, s, 0, 0, 0);
      s = __builtin_amdgcn_mfma_f32_16x16x32_bf16(qa1, b1, s, 0, 0, 0);
      sf[f] = s * 0.125f;
    }
    if (kt == qt) {
#pragma unroll
      for (int f = 0; f < 4; ++f) {
        int key = qt * 64 + f * 16 + (lane & 15);
#pragma unroll
        for (int r = 0; r < 4; ++r) {
          int qg = qt * 64 + wave * 16 + ((lane >> 4) << 2) + r;
          if (key > qg) sf[f][r] = -1e30f;
        }
      }
    }

    // online softmax; denominator WITHOUT decay, numerator (P) WITH decay
#pragma unroll
    for (int r = 0; r < 4; ++r) {
      float mx = fmaxf(fmaxf(sf[0][r], sf[1][r]), fmaxf(sf[2][r], sf[3][r]));
      mx = fmaxf(mx, __shfl_xor(mx, 1));
      mx = fmaxf(mx, __shfl_xor(mx, 2));
      mx = fmaxf(mx, __shfl_xor(mx, 4));
      mx = fmaxf(mx, __shfl_xor(mx, 8));
      float mnew = fmaxf(mrow[r], mx);
      float sc = __expf(mrow[r] - mnew);
      mrow[r] = mnew;
      lrow[r] *= sc;
#pragma unroll
      for (int n = 0; n < 4; ++n) acc[n][r] *= sc;
      int qg = qt * 64 + wave * 16 + ((lane >> 4) << 2) + r;
      int prow = (wave * 16 + ((lane >> 4) << 2) + r) * 72 + (lane & 15);
#pragma unroll
      for (int f = 0; f < 4; ++f) {
        float p = __expf(sf[f][r] - mnew);
        lrow[r] += p;                      // per-lane partial, reduced at end
        int key = kt * 64 + f * 16 + (lane & 15);
        int di = qg - key; di = di < 0 ? 0 : di;
        plds[prow + f * 16] = f2bf(p * decay[di]);
      }
    }
    __syncthreads();

    // y += P @ V   (A = P [q][key], B = V [key][d] read from V^T)
#pragma unroll
    for (int ks = 0; ks < 2; ++ks) {
      bf16x8 pa = *(const bf16x8*)((const u16*)plds +
                    (wave * 16 + (lane & 15)) * 72 + ks * 32 + ((lane >> 4) << 3));
#pragma unroll
      for (int n = 0; n < 4; ++n) {
        bf16x8 vb = *(const bf16x8*)((const u16*)vt +
                      (n * 16 + (lane & 15)) * 72 + ks * 32 + ((lane >> 4) << 3));
        acc[n] = __builtin_amdgcn_mfma_f32_16x16x32_bf16(pa, vb, acc[n], 0, 0, 0);
      }
    }
    __syncthreads();
  }

  // finalize: reduce denominator across the 16-lane group, scale, store
#pragma unroll
  for (int r = 0; r < 4; ++r) {
    float lv = lrow[r];
    lv += __shfl_xor(lv, 1);
    lv += __shfl_xor(lv, 2);
    lv += __shfl_xor(lv, 4);
    lv += __shfl_xor(lv, 8);
    lrow[r] = 1.0f / lv;
  }
#pragma unroll
  for (int n = 0; n < 4; ++n) {
    int d = h * 64 + n * 16 + (lane & 15);
#pragma unroll
    for (int r = 0; r < 4; ++r) {
      int t = qt * 64 + wave * 16 + ((lane >> 4) << 2) + r;
      yb[((size_t)b * T_ + t) * 1024 + d] = f2bf(acc[n][r] * lrow[r]);
    }
  }
}

// ---------------- launch ----------------
extern "C" void kernel_launch(void* const* d_in, const int* in_sizes, int n_in,
                              void* d_out, int out_size, void* d_ws, size_t ws_size,
                              hipStream_t stream) {
  const float* x  = (const float*)d_in[0];
  const float* Wa = (const float*)d_in[1];
  const float* Wp = (const float*)d_in[2];
  float* out = (float*)d_out;
  char* ws = (char*)d_ws;

  // workspace layout (bytes)
  u16*   xb    = (u16*)(ws + 0);           //  8,388,608  x as bf16 [4096][1024]
  u16*   WaT   = (u16*)(ws + 8388608);     //  6,291,456  W_attn^T bf16 [3072][1024]
  u16*   WpT   = (u16*)(ws + 14680064);    //  2,097,152  W_proj^T bf16 [1024][1024]
  u16*   qkvb  = (u16*)(ws + 16777216);    // 25,165,824  qkv bf16 [3][2][16][2048][64]
  u16*   yb    = (u16*)(ws + 41943040);    //  8,388,608  y bf16 [4096][1024]
  float* decay = (float*)(ws + 50331648);  //      8,192  decay table

  cvt4_kernel<<<4096, 256, 0, stream>>>(x, xb, B_ * T_ * C_);
  transpose_cvt_kernel<<<dim3(96, 32), 256, 0, stream>>>(Wa, WaT, C_, N3_);
  transpose_cvt_kernel<<<dim3(32, 32), 256, 0, stream>>>(Wp, WpT, C_, C_);
  decay_init_kernel<<<8, 256, 0, stream>>>(decay);

  gemm128_kernel<0><<<dim3(N3_ / 128, 32), 256, 0, stream>>>(xb, WaT, nullptr, qkvb,
                                                             B_ * T_, N3_, C_);
  attn_kernel<<<dim3(32, 32), 256, 0, stream>>>(qkvb, decay, yb);
  gemm128_kernel<1><<<dim3(1024 / 128, 32), 256, 0, stream>>>(yb, WpT, out, nullptr,
                                                              B_ * T_, 1024, 1024);
}

// Round 2
// 169.271 us; speedup vs baseline: 1.3049x; 1.3049x over previous
//
#include <hip/hip_runtime.h>
#include <math.h>

// Requires ws_size >= 50,339,840 bytes (~48 MiB) of scratch.
#define B_  2
#define T_  2048
#define C_  1024
#define NH_ 16
#define HD_ 64
#define N3_ 3072

typedef float f32x4 __attribute__((ext_vector_type(4)));
typedef short bf16x8 __attribute__((ext_vector_type(8)));
typedef unsigned short u16;

__device__ __forceinline__ u16 f2bf(float x) {
  unsigned int u = __builtin_bit_cast(unsigned int, x);
  u += 0x7FFFu + ((u >> 16) & 1u);
  return (u16)(u >> 16);
}

#define GLD16(g, l) __builtin_amdgcn_global_load_lds( \
    (__attribute__((address_space(1))) void*)(g), \
    (__attribute__((address_space(3))) void*)(l), 16, 0, 0)

// ---------------- converts ----------------
__global__ __launch_bounds__(256) void cvt4_kernel(const float* __restrict__ in,
                                                   u16* __restrict__ out, int n) {
  int i = (blockIdx.x * 256 + threadIdx.x) * 4;
  if (i >= n) return;
  float4 v = *(const float4*)(in + i);
  ushort4 o;
  o.x = f2bf(v.x); o.y = f2bf(v.y); o.z = f2bf(v.z); o.w = f2bf(v.w);
  *(ushort4*)(out + i) = o;
}

// out[c][r] = bf16(in[r][c]); R,Cc multiples of 32
__global__ __launch_bounds__(256) void transpose_cvt_kernel(const float* __restrict__ in,
                                                            u16* __restrict__ out,
                                                            int R, int Cc) {
  __shared__ float tile[32][33];
  int c0 = blockIdx.x * 32, r0 = blockIdx.y * 32;
  int tx = threadIdx.x & 31, ty = threadIdx.x >> 5;
#pragma unroll
  for (int rr = ty; rr < 32; rr += 8)
    tile[rr][tx] = in[(size_t)(r0 + rr) * Cc + c0 + tx];
  __syncthreads();
#pragma unroll
  for (int rr = ty; rr < 32; rr += 8)
    out[(size_t)(c0 + rr) * R + r0 + tx] = f2bf(tile[tx][rr]);
}

__global__ __launch_bounds__(256) void decay_init_kernel(float* __restrict__ decay) {
  int d = blockIdx.x * 256 + threadIdx.x;
  if (d >= T_) return;
  float v = 1.0f;
  if (d >= 15) v = 1.0f - powf((float)(d - 15) * (1.0f / 2032.0f), 0.36787944117144233f);
  decay[d] = v;
}

// ---------------- GEMM: C[M][N] = A[M][K] * Bt[N][K]^T ----------------
// 128x128 tile, 4 waves (2x2 of 64x64), BK=32, global_load_lds w/ XOR-swizzled src.
// MODE 0: store bf16 into qkv split layout [which][b][h][t][d]; Q pre-scaled by 1/8
// MODE 1: store fp32 row-major
template<int MODE>
__global__ __launch_bounds__(256) void gemm128_kernel(
    const u16* __restrict__ A, const u16* __restrict__ Bt,
    float* __restrict__ Cf, u16* __restrict__ Cq,
    int M, int N, int K)
{
  __shared__ char lds[16384];   // A tile [128][32] @0, Bt tile [128][32] @8192
  const int lane = threadIdx.x & 63;
  const int wave = threadIdx.x >> 6;
  const int m0 = blockIdx.y << 7;
  const int n0 = blockIdx.x << 7;
  const int wm = wave >> 1, wn = wave & 1;

  f32x4 acc[4][4] = {};

  for (int k0 = 0; k0 < K; k0 += 32) {
#pragma unroll
    for (int c = 0; c < 2; ++c) {
      int chunk = wave * 2048 + c * 1024;
      int row = (chunk >> 6) + (lane >> 2);
      int wb = ((lane & 3) << 4) ^ ((row & 3) << 4);   // pre-swizzled source col
      GLD16((const char*)(A  + (size_t)(m0 + row) * K + k0) + wb, lds + chunk);
      GLD16((const char*)(Bt + (size_t)(n0 + row) * K + k0) + wb, lds + 8192 + chunk);
    }
    __syncthreads();
    bf16x8 af[4], bfr[4];
#pragma unroll
    for (int m = 0; m < 4; ++m) {
      int row = wm * 64 + m * 16 + (lane & 15);
      int wb = ((lane >> 4) << 4) ^ ((row & 3) << 4);
      af[m] = *(const bf16x8*)(lds + row * 64 + wb);
    }
#pragma unroll
    for (int n = 0; n < 4; ++n) {
      int row = wn * 64 + n * 16 + (lane & 15);
      int wb = ((lane >> 4) << 4) ^ ((row & 3) << 4);
      bfr[n] = *(const bf16x8*)(lds + 8192 + row * 64 + wb);
    }
#pragma unroll
    for (int m = 0; m < 4; ++m)
#pragma unroll
      for (int n = 0; n < 4; ++n)
        acc[m][n] = __builtin_amdgcn_mfma_f32_16x16x32_bf16(af[m], bfr[n], acc[m][n], 0, 0, 0);
    __syncthreads();
  }

#pragma unroll
  for (int m = 0; m < 4; ++m) {
    int grow0 = m0 + wm * 64 + m * 16 + ((lane >> 4) << 2);
#pragma unroll
    for (int n = 0; n < 4; ++n) {
      int gcol = n0 + wn * 64 + n * 16 + (lane & 15);
      f32x4 v = acc[m][n];
#pragma unroll
      for (int r = 0; r < 4; ++r) {
        int grow = grow0 + r;
        if (MODE == 0) {
          int bb = grow >> 11, tt = grow & 2047;
          int which = gcol >> 10, rem = gcol & 1023;
          int hh = rem >> 6, dd = rem & 63;
          size_t idx = ((((size_t)which * 2 + bb) * 16 + hh) * 2048 + tt) * 64 + dd;
          float ov = (which == 0) ? v[r] * 0.125f : v[r];  // fold 1/sqrt(hd) into Q
          Cq[idx] = f2bf(ov);
        } else {
          Cf[(size_t)grow * N + gcol] = v[r];
        }
      }
    }
  }
}

// ---------------- fused flash attention with post-softmax decay ----------------
// grid: (16 q-blocks of 128 rows, 32 bh); block: 4 waves, each wave owns 32 q-rows.
// Fixed-max softmax (no online rescale): p = exp(s), masked s = -1e30 -> p = 0.
__global__ __launch_bounds__(256, 3) void attn_kernel(
    const u16* __restrict__ qkvb, const float* __restrict__ decay,
    u16* __restrict__ yb)
{
  __shared__ char klds[8192];        // K tile [64 keys][128B], XOR-swizzled rows
  __shared__ u16 vt[64 * 72];        // V^T [d][key], stride 72
  __shared__ u16 plds[128 * 76];     // P   [q][key], stride 76 (wave-private rows)
  __shared__ float sdec[2048];       // decay table

  const int lane = threadIdx.x & 63;
  const int wave = threadIdx.x >> 6;
  const int qb = 15 - (int)blockIdx.x;     // heavy blocks dispatch first
  const int bh = blockIdx.y;
  const int b = bh >> 4, h = bh & 15;

  const u16* Q  = qkvb + (((size_t)0 * B_ + b) * NH_ + h) * T_ * HD_;
  const u16* Kg = qkvb + (((size_t)1 * B_ + b) * NH_ + h) * T_ * HD_;
  const u16* Vg = qkvb + (((size_t)2 * B_ + b) * NH_ + h) * T_ * HD_;

  const int wrow = qb * 128 + wave * 32;

  {  // decay -> LDS
    const float4* s4 = (const float4*)decay;
    float4* dd = (float4*)sdec;
    dd[threadIdx.x * 2]     = s4[threadIdx.x * 2];
    dd[threadIdx.x * 2 + 1] = s4[threadIdx.x * 2 + 1];
  }

  bf16x8 qa[2][2];
#pragma unroll
  for (int g = 0; g < 2; ++g) {
    const u16* qp = Q + (size_t)(wrow + g * 16 + (lane & 15)) * HD_ + ((lane >> 4) << 3);
    qa[g][0] = *(const bf16x8*)(qp);
    qa[g][1] = *(const bf16x8*)(qp + 32);
  }

  f32x4 acc[2][4] = {};
  float lsum[2][4] = {};

  const int nkt = 2 * qb + 2;
  for (int kt = 0; kt < nkt; ++kt) {
    // stage K tile (global_load_lds, pre-swizzled source)
#pragma unroll
    for (int c = 0; c < 2; ++c) {
      int chunk = wave * 2048 + c * 1024;
      int row = (chunk >> 7) + (lane >> 3);
      int wb = ((lane & 7) << 4) ^ ((row & 7) << 4);
      GLD16((const char*)(Kg + (size_t)(kt * 64 + row) * HD_) + wb, klds + chunk);
    }
    // stage V^T via registers
    {
      int d0 = wave << 4;
      const u16* src = Vg + (size_t)(kt * 64 + lane) * HD_ + d0;
      bf16x8 v0 = *(const bf16x8*)(src);
      bf16x8 v1 = *(const bf16x8*)(src + 8);
#pragma unroll
      for (int j = 0; j < 8; ++j) {
        vt[(d0 + j) * 72 + lane]     = (u16)v0[j];
        vt[(d0 + 8 + j) * 72 + lane] = (u16)v1[j];
      }
    }
    __syncthreads();   // K,V (and first-iter sdec) ready

    if (64 * kt <= wrow + 31) {       // wave has >=1 unmasked row in this tile
      // K fragments (shared across both row-groups)
      bf16x8 kf[4][2];
#pragma unroll
      for (int f = 0; f < 4; ++f) {
        int krow = f * 16 + (lane & 15);
        int base = krow * 128;
        int msk = (krow & 7) << 4;
        kf[f][0] = *(const bf16x8*)(klds + base + ((((lane >> 4) << 4)) ^ msk));
        kf[f][1] = *(const bf16x8*)(klds + base + ((64 + ((lane >> 4) << 4)) ^ msk));
      }
      const bool tail = (64 * kt + 63 > wrow);
#pragma unroll
      for (int g = 0; g < 2; ++g) {
        f32x4 s[4] = {};
#pragma unroll
        for (int f = 0; f < 4; ++f) {
          s[f] = __builtin_amdgcn_mfma_f32_16x16x32_bf16(qa[g][0], kf[f][0], s[f], 0, 0, 0);
          s[f] = __builtin_amdgcn_mfma_f32_16x16x32_bf16(qa[g][1], kf[f][1], s[f], 0, 0, 0);
        }
        int rbase = wrow + g * 16 + ((lane >> 4) << 2);
        if (tail) {
#pragma unroll
          for (int f = 0; f < 4; ++f) {
            int key = kt * 64 + f * 16 + (lane & 15);
#pragma unroll
            for (int r = 0; r < 4; ++r)
              if (key > rbase + r) s[f][r] = -1e30f;
          }
        }
#pragma unroll
        for (int r = 0; r < 4; ++r) {
          int qg = rbase + r;
          u16* pr = plds + (size_t)(wave * 32 + g * 16 + ((lane >> 4) << 2) + r) * 76 + (lane & 15);
          float lacc = 0.0f;
#pragma unroll
          for (int f = 0; f < 4; ++f) {
            float p = __expf(s[f][r]);           // Q pre-scaled by 1/8
            int di = qg - (kt * 64 + f * 16 + (lane & 15));
            di = di < 0 ? 0 : di;
            pr[f * 16] = f2bf(p * sdec[di]);
            lacc += p;
          }
          lsum[g][r] += lacc;
        }
      }
      // V fragments (shared across both row-groups)
      bf16x8 vf[4][2];
#pragma unroll
      for (int n = 0; n < 4; ++n)
#pragma unroll
        for (int ks = 0; ks < 2; ++ks)
          vf[n][ks] = *(const bf16x8*)((const u16*)vt +
                        (n * 16 + (lane & 15)) * 72 + ks * 32 + ((lane >> 4) << 3));
#pragma unroll
      for (int g = 0; g < 2; ++g)
#pragma unroll
        for (int ks = 0; ks < 2; ++ks) {
          bf16x8 pa = *(const bf16x8*)((const u16*)plds +
                        (size_t)(wave * 32 + g * 16 + (lane & 15)) * 76 + ks * 32 + ((lane >> 4) << 3));
#pragma unroll
          for (int n = 0; n < 4; ++n)
            acc[g][n] = __builtin_amdgcn_mfma_f32_16x16x32_bf16(pa, vf[n][ks], acc[g][n], 0, 0, 0);
        }
    }
    __syncthreads();   // protect klds/vt before next stage
  }

  // finalize: reduce denominator across 16-lane quadrant, scale, store
#pragma unroll
  for (int g = 0; g < 2; ++g)
#pragma unroll
    for (int r = 0; r < 4; ++r) {
      float lv = lsum[g][r];
      lv += __shfl_xor(lv, 1);
      lv += __shfl_xor(lv, 2);
      lv += __shfl_xor(lv, 4);
      lv += __shfl_xor(lv, 8);
      lsum[g][r] = 1.0f / lv;
    }
#pragma unroll
  for (int g = 0; g < 2; ++g)
#pragma unroll
    for (int n = 0; n < 4; ++n) {
      int d = h * 64 + n * 16 + (lane & 15);
#pragma unroll
      for (int r = 0; r < 4; ++r) {
        int t = wrow + g * 16 + ((lane >> 4) << 2) + r;
        yb[((size_t)b * T_ + t) * 1024 + d] = f2bf(acc[g][n][r] * lsum[g][r]);
      }
    }
}

// ---------------- launch ----------------
extern "C" void kernel_launch(void* const* d_in, const int* in_sizes, int n_in,
                              void* d_out, int out_size, void* d_ws, size_t ws_size,
                              hipStream_t stream) {
  const float* x  = (const float*)d_in[0];
  const float* Wa = (const float*)d_in[1];
  const float* Wp = (const float*)d_in[2];
  float* out = (float*)d_out;
  char* ws = (char*)d_ws;

  // workspace layout (bytes)
  u16*   xb    = (u16*)(ws + 0);           //  8,388,608  x as bf16 [4096][1024]
  u16*   WaT   = (u16*)(ws + 8388608);     //  6,291,456  W_attn^T bf16 [3072][1024]
  u16*   WpT   = (u16*)(ws + 14680064);    //  2,097,152  W_proj^T bf16 [1024][1024]
  u16*   qkvb  = (u16*)(ws + 16777216);    // 25,165,824  qkv bf16 [3][2][16][2048][64]
  u16*   yb    = (u16*)(ws + 41943040);    //  8,388,608  y bf16 [4096][1024]
  float* decay = (float*)(ws + 50331648);  //      8,192  decay table

  cvt4_kernel<<<4096, 256, 0, stream>>>(x, xb, B_ * T_ * C_);
  transpose_cvt_kernel<<<dim3(96, 32), 256, 0, stream>>>(Wa, WaT, C_, N3_);
  transpose_cvt_kernel<<<dim3(32, 32), 256, 0, stream>>>(Wp, WpT, C_, C_);
  decay_init_kernel<<<8, 256, 0, stream>>>(decay);

  gemm128_kernel<0><<<dim3(N3_ / 128, 32), 256, 0, stream>>>(xb, WaT, nullptr, qkvb,
                                                             B_ * T_, N3_, C_);
  attn_kernel<<<dim3(16, 32), 256, 0, stream>>>(qkvb, decay, yb);
  gemm128_kernel<1><<<dim3(1024 / 128, 32), 256, 0, stream>>>(yb, WpT, out, nullptr,
                                                              B_ * T_, 1024, 1024);
}

// Round 3
// 161.185 us; speedup vs baseline: 1.3704x; 1.0502x over previous
//
#include <hip/hip_runtime.h>
#include <math.h>

// ws footprint: 50,339,840 bytes (same as R1/R2).
#define B_  2
#define T_  2048
#define C_  1024
#define NH_ 16
#define HD_ 64
#define N3_ 3072

typedef float f32x4 __attribute__((ext_vector_type(4)));
typedef short bf16x8 __attribute__((ext_vector_type(8)));
typedef unsigned short u16;

// Q prescale: 1/sqrt(64) * log2(e), so softmax uses exp2 directly.
#define QSCALE 0.18033688011112042f

#if __has_builtin(__builtin_amdgcn_exp2f)
#define EXP2(x) __builtin_amdgcn_exp2f(x)
#else
#define EXP2(x) exp2f(x)
#endif

__device__ __forceinline__ u16 f2bf(float x) {
  unsigned int u = __builtin_bit_cast(unsigned int, x);
  u += 0x7FFFu + ((u >> 16) & 1u);
  return (u16)(u >> 16);
}

#define GLD16(g, l) __builtin_amdgcn_global_load_lds( \
    (__attribute__((address_space(1))) void*)(g), \
    (__attribute__((address_space(3))) void*)(l), 16, 0, 0)

// ---------------- converts ----------------
__global__ __launch_bounds__(256) void cvt4_kernel(const float* __restrict__ in,
                                                   u16* __restrict__ out, int n) {
  int i = (blockIdx.x * 256 + threadIdx.x) * 4;
  if (i >= n) return;
  float4 v = *(const float4*)(in + i);
  ushort4 o;
  o.x = f2bf(v.x); o.y = f2bf(v.y); o.z = f2bf(v.z); o.w = f2bf(v.w);
  *(ushort4*)(out + i) = o;
}

// out[c][r] = bf16(in[r][c]); R,Cc multiples of 32
__global__ __launch_bounds__(256) void transpose_cvt_kernel(const float* __restrict__ in,
                                                            u16* __restrict__ out,
                                                            int R, int Cc) {
  __shared__ float tile[32][33];
  int c0 = blockIdx.x * 32, r0 = blockIdx.y * 32;
  int tx = threadIdx.x & 31, ty = threadIdx.x >> 5;
#pragma unroll
  for (int rr = ty; rr < 32; rr += 8)
    tile[rr][tx] = in[(size_t)(r0 + rr) * Cc + c0 + tx];
  __syncthreads();
#pragma unroll
  for (int rr = ty; rr < 32; rr += 8)
    out[(size_t)(c0 + rr) * R + r0 + tx] = f2bf(tile[tx][rr]);
}

__global__ __launch_bounds__(256) void decay_init_kernel(float* __restrict__ decay) {
  int d = blockIdx.x * 256 + threadIdx.x;
  if (d >= T_) return;
  float v = 1.0f;
  if (d >= 15) v = 1.0f - powf((float)(d - 15) * (1.0f / 2032.0f), 0.36787944117144233f);
  decay[d] = v;
}

// V [bh][t][d] -> VT [bh][d][t], per-head 64x64 tiles via LDS
__global__ __launch_bounds__(256) void vtrans_kernel(const u16* __restrict__ V,
                                                     u16* __restrict__ VT) {
  __shared__ u16 tile[64][72];
  int bh = blockIdx.y, t0 = blockIdx.x * 64;
  const u16* src = V + ((size_t)bh * T_ + t0) * HD_;
  int r = threadIdx.x >> 2;
  int c8 = (threadIdx.x & 3) * 16;
  *(bf16x8*)(&tile[r][c8])     = *(const bf16x8*)(src + (size_t)r * HD_ + c8);
  *(bf16x8*)(&tile[r][c8 + 8]) = *(const bf16x8*)(src + (size_t)r * HD_ + c8 + 8);
  __syncthreads();
  int d = threadIdx.x >> 2;
  int tc = (threadIdx.x & 3) * 16;
  u16 outv[16];
#pragma unroll
  for (int j = 0; j < 16; ++j) outv[j] = tile[tc + j][d];
  u16* dst = VT + ((size_t)bh * HD_ + d) * T_ + t0 + tc;
  *(bf16x8*)(dst)     = *(bf16x8*)(outv);
  *(bf16x8*)(dst + 8) = *(bf16x8*)(outv + 8);
}

// ---------------- GEMM: C[M][N] = A[M][K] * Bt[N][K]^T ----------------
// 128x128 tile, 4 waves, BK=32, double-buffered LDS, 1 barrier/iter.
// MODE 0: bf16 out -> Q,K into qkb [which][bh][t][d] (Q prescaled); V into Vt [bh][t][d]
// MODE 1: fp32 row-major
template<int MODE>
__global__ __launch_bounds__(256, 3) void gemm128_kernel(
    const u16* __restrict__ A, const u16* __restrict__ Bt,
    float* __restrict__ Cf, u16* __restrict__ Cq, u16* __restrict__ Vt,
    int M, int N, int K)
{
  __shared__ char lds[32768];   // buf b: A tile @b*16384, Bt tile @b*16384+8192
  const int lane = threadIdx.x & 63;
  const int wave = threadIdx.x >> 6;
  const int m0 = blockIdx.y << 7;
  const int n0 = blockIdx.x << 7;
  const int wm = wave >> 1, wn = wave & 1;

  f32x4 acc[4][4] = {};

#define GSTAGE(buf, k0)                                                          \
  {                                                                              \
    _Pragma("unroll")                                                            \
    for (int c = 0; c < 2; ++c) {                                                \
      int chunk = wave * 2048 + c * 1024;                                        \
      int row = (chunk >> 6) + (lane >> 2);                                      \
      int wb = ((lane & 3) << 4) ^ ((row & 3) << 4);                             \
      GLD16((const char*)(A  + (size_t)(m0 + row) * K + (k0)) + wb,              \
            lds + (buf) * 16384 + chunk);                                        \
      GLD16((const char*)(Bt + (size_t)(n0 + row) * K + (k0)) + wb,              \
            lds + (buf) * 16384 + 8192 + chunk);                                 \
    }                                                                            \
  }

  GSTAGE(0, 0);
  __syncthreads();

  for (int k0 = 0; k0 < K; k0 += 32) {
    const int cur = (k0 >> 5) & 1;
    if (k0 + 32 < K) GSTAGE(cur ^ 1, k0 + 32);
    const char* base = lds + cur * 16384;
    bf16x8 af[4], bfr[4];
#pragma unroll
    for (int m = 0; m < 4; ++m) {
      int row = wm * 64 + m * 16 + (lane & 15);
      int wb = ((lane >> 4) << 4) ^ ((row & 3) << 4);
      af[m] = *(const bf16x8*)(base + row * 64 + wb);
    }
#pragma unroll
    for (int n = 0; n < 4; ++n) {
      int row = wn * 64 + n * 16 + (lane & 15);
      int wb = ((lane >> 4) << 4) ^ ((row & 3) << 4);
      bfr[n] = *(const bf16x8*)(base + 8192 + row * 64 + wb);
    }
    __builtin_amdgcn_s_setprio(1);
#pragma unroll
    for (int m = 0; m < 4; ++m)
#pragma unroll
      for (int n = 0; n < 4; ++n)
        acc[m][n] = __builtin_amdgcn_mfma_f32_16x16x32_bf16(af[m], bfr[n], acc[m][n], 0, 0, 0);
    __builtin_amdgcn_s_setprio(0);
    __syncthreads();
  }

#pragma unroll
  for (int m = 0; m < 4; ++m) {
    int grow0 = m0 + wm * 64 + m * 16 + ((lane >> 4) << 2);
#pragma unroll
    for (int n = 0; n < 4; ++n) {
      int gcol = n0 + wn * 64 + n * 16 + (lane & 15);
      f32x4 v = acc[m][n];
#pragma unroll
      for (int r = 0; r < 4; ++r) {
        int grow = grow0 + r;
        if (MODE == 0) {
          int bb = grow >> 11, tt = grow & 2047;
          int which = gcol >> 10, rem = gcol & 1023;
          int hh = rem >> 6, dd = rem & 63;
          if (which < 2) {
            float ov = (which == 0) ? v[r] * QSCALE : v[r];
            Cq[((size_t)(which * 32 + bb * 16 + hh) * 2048 + tt) * 64 + dd] = f2bf(ov);
          } else {
            Vt[((size_t)(bb * 16 + hh) * 2048 + tt) * 64 + dd] = f2bf(v[r]);
          }
        } else {
          Cf[(size_t)grow * N + gcol] = v[r];
        }
      }
    }
  }
#undef GSTAGE
}

// ---------------- fused flash attention with post-softmax decay ----------------
// grid (32 qt, 32 bh); 4 waves, wave owns 16 q-rows; dbuf K/V, 1 barrier/iter.
// Fixed-max softmax: p = exp2(s) (Q pre-scaled by log2e/8), masked s -> -1e30.
__global__ __launch_bounds__(256, 3) void attn_kernel(
    const u16* __restrict__ qkb, const u16* __restrict__ vtg,
    const float* __restrict__ decayg, u16* __restrict__ yb)
{
  __shared__ char klds[2][8192];   // K tile [64 keys][128B], XOR-swizzled
  __shared__ char vlds[2][8192];   // V^T tile [64 d][128B keys], XOR-swizzled
  __shared__ u16 plds[64 * 76];    // P [q][key], stride 76, wave-private rows

  const int lane = threadIdx.x & 63;
  const int wave = threadIdx.x >> 6;
  const int quad = lane >> 4;
  const int l15 = lane & 15;
  const int qt = 31 - (int)blockIdx.x;   // heavy tiles dispatch first
  const int bh = blockIdx.y;
  const int b = bh >> 4, h = bh & 15;

  const u16* Q   = qkb + (size_t)bh * T_ * HD_;
  const u16* Kg  = qkb + (size_t)(32 + bh) * T_ * HD_;
  const u16* VTg = vtg + (size_t)bh * HD_ * T_;

  const int wrow = qt * 64 + wave * 16;
  const int rbase = wrow + quad * 4;

  bf16x8 qa[2];
  {
    const u16* qp = Q + (size_t)(wrow + l15) * HD_ + quad * 8;
    qa[0] = *(const bf16x8*)(qp);
    qa[1] = *(const bf16x8*)(qp + 32);
  }

  f32x4 acc[4] = {};
  f32x4 lsum = {};

#define ASTAGE(buf, kt)                                                          \
  {                                                                              \
    _Pragma("unroll")                                                            \
    for (int c = 0; c < 2; ++c) {                                                \
      int chunk = wave * 2048 + c * 1024;                                        \
      int row = (chunk >> 7) + (lane >> 3);                                      \
      int wb = ((lane & 7) << 4) ^ ((row & 7) << 4);                             \
      GLD16((const char*)(Kg + (size_t)((kt) * 64 + row) * HD_) + wb,            \
            klds[buf] + chunk);                                                  \
      GLD16((const char*)(VTg + (size_t)row * T_ + (kt) * 64) + wb,              \
            vlds[buf] + chunk);                                                  \
    }                                                                            \
  }

  ASTAGE(0, 0);
  __syncthreads();

  const int nkt = qt + 1;
  for (int kt = 0; kt < nkt; ++kt) {
    const int cur = kt & 1;
    if (kt + 1 < nkt) ASTAGE(cur ^ 1, kt + 1);

    // S = Q K^T (already in log2 domain)
    f32x4 s[4];
    __builtin_amdgcn_s_setprio(1);
#pragma unroll
    for (int f = 0; f < 4; ++f) {
      int krow = f * 16 + l15;
      int base = krow * 128;
      int msk = (krow & 7) << 4;
      bf16x8 k0 = *(const bf16x8*)(klds[cur] + base + ((quad * 16) ^ msk));
      bf16x8 k1 = *(const bf16x8*)(klds[cur] + base + ((64 + quad * 16) ^ msk));
      f32x4 t = {};
      t = __builtin_amdgcn_mfma_f32_16x16x32_bf16(qa[0], k0, t, 0, 0, 0);
      t = __builtin_amdgcn_mfma_f32_16x16x32_bf16(qa[1], k1, t, 0, 0, 0);
      s[f] = t;
    }
    __builtin_amdgcn_s_setprio(0);

    if (kt == qt) {   // diagonal tile: causal mask
#pragma unroll
      for (int f = 0; f < 4; ++f) {
        int key = kt * 64 + f * 16 + l15;
#pragma unroll
        for (int r = 0; r < 4; ++r)
          if (key > rbase + r) s[f][r] = -1e30f;
      }
    }

    // softmax numerator/denominator; decay from global (L1-hot), clamp idx
#pragma unroll
    for (int f = 0; f < 4; ++f) {
      int key = kt * 64 + f * 16 + l15;
      int di0 = rbase - key;
      f32x4 p;
#pragma unroll
      for (int r = 0; r < 4; ++r) p[r] = EXP2(s[f][r]);
      lsum += p;
      u16* pw = plds + (size_t)(wave * 16 + quad * 4) * 76 + l15 + f * 16;
#pragma unroll
      for (int r = 0; r < 4; ++r) {
        int idx = di0 + r; idx = idx < 0 ? 0 : idx;
        pw[(size_t)r * 76] = f2bf(p[r] * decayg[idx]);
      }
    }

    // y += P @ V  (pa wave-private, no barrier needed between write and read)
    __builtin_amdgcn_s_setprio(1);
#pragma unroll
    for (int ks = 0; ks < 2; ++ks) {
      bf16x8 pa = *(const bf16x8*)(plds + (size_t)(wave * 16 + l15) * 76 + ks * 32 + quad * 8);
#pragma unroll
      for (int n = 0; n < 4; ++n) {
        int vrow = n * 16 + l15;
        int mskv = (vrow & 7) << 4;
        bf16x8 vb = *(const bf16x8*)(vlds[cur] + vrow * 128 + ((ks * 64 + quad * 16) ^ mskv));
        acc[n] = __builtin_amdgcn_mfma_f32_16x16x32_bf16(pa, vb, acc[n], 0, 0, 0);
      }
    }
    __builtin_amdgcn_s_setprio(0);
    __syncthreads();   // drains vmcnt(0): next buffer staged + everyone done with cur
  }
#undef ASTAGE

  // finalize: reduce denominator across 16-lane group, scale, store
  f32x4 li = lsum;
#pragma unroll
  for (int d = 1; d < 16; d <<= 1) {
#pragma unroll
    for (int r = 0; r < 4; ++r) li[r] += __shfl_xor(li[r], d);
  }
#pragma unroll
  for (int n = 0; n < 4; ++n) {
    int d = h * 64 + n * 16 + l15;
#pragma unroll
    for (int r = 0; r < 4; ++r) {
      int t = wrow + quad * 4 + r;
      yb[((size_t)b * T_ + t) * 1024 + d] = f2bf(acc[n][r] / li[r]);
    }
  }
}

// ---------------- launch ----------------
extern "C" void kernel_launch(void* const* d_in, const int* in_sizes, int n_in,
                              void* d_out, int out_size, void* d_ws, size_t ws_size,
                              hipStream_t stream) {
  const float* x  = (const float*)d_in[0];
  const float* Wa = (const float*)d_in[1];
  const float* Wp = (const float*)d_in[2];
  float* out = (float*)d_out;
  char* ws = (char*)d_ws;

  // workspace layout (bytes), total 50,339,840
  u16*   xb    = (u16*)(ws + 0);           //  8,388,608  x bf16 [4096][1024]; reused as yb
  u16*   WaT   = (u16*)(ws + 8388608);     //  6,291,456  W_attn^T bf16 [3072][1024]
  u16*   WpT   = (u16*)(ws + 14680064);    //  2,097,152  W_proj^T bf16 [1024][1024]
  u16*   qkb   = (u16*)(ws + 16777216);    // 16,777,216  Q,K bf16 [2][32][2048][64]
  u16*   Vtmp  = (u16*)(ws + 33554432);    //  8,388,608  V bf16 [32][2048][64]
  u16*   VT    = (u16*)(ws + 41943040);    //  8,388,608  V^T bf16 [32][64][2048]
  float* decay = (float*)(ws + 50331648);  //      8,192  decay table f32[2048]
  u16*   yb    = xb;                       //  xb is dead after gemm0

  cvt4_kernel<<<4096, 256, 0, stream>>>(x, xb, B_ * T_ * C_);
  transpose_cvt_kernel<<<dim3(96, 32), 256, 0, stream>>>(Wa, WaT, C_, N3_);
  transpose_cvt_kernel<<<dim3(32, 32), 256, 0, stream>>>(Wp, WpT, C_, C_);
  decay_init_kernel<<<8, 256, 0, stream>>>(decay);

  gemm128_kernel<0><<<dim3(N3_ / 128, 32), 256, 0, stream>>>(
      xb, WaT, nullptr, qkb, Vtmp, B_ * T_, N3_, C_);
  vtrans_kernel<<<dim3(32, 32), 256, 0, stream>>>(Vtmp, VT);
  attn_kernel<<<dim3(32, 32), 256, 0, stream>>>(qkb, VT, decay, yb);
  gemm128_kernel<1><<<dim3(1024 / 128, 32), 256, 0, stream>>>(
      yb, WpT, out, nullptr, nullptr, B_ * T_, 1024, 1024);
}

// Round 4
// 130.131 us; speedup vs baseline: 1.6974x; 1.2386x over previous
//
#include <hip/hip_runtime.h>
#include <math.h>

// ws footprint: 50,339,840 bytes.
#define B_  2
#define T_  2048
#define C_  1024
#define NH_ 16
#define HD_ 64
#define N3_ 3072

typedef float f32x4 __attribute__((ext_vector_type(4)));
typedef short bf16x8 __attribute__((ext_vector_type(8)));
typedef unsigned short u16;

// Q prescale: 1/sqrt(64) * log2(e), so softmax uses exp2 directly.
#define QSCALE 0.18033688011112042f

#if __has_builtin(__builtin_amdgcn_exp2f)
#define EXP2(x) __builtin_amdgcn_exp2f(x)
#else
#define EXP2(x) exp2f(x)
#endif

__device__ __forceinline__ u16 f2bf(float x) {
  unsigned int u = __builtin_bit_cast(unsigned int, x);
  u += 0x7FFFu + ((u >> 16) & 1u);
  return (u16)(u >> 16);
}

#define GLD16(g, l) __builtin_amdgcn_global_load_lds( \
    (__attribute__((address_space(1))) void*)(g), \
    (__attribute__((address_space(3))) void*)(l), 16, 0, 0)

// ---------------- converts ----------------
__global__ __launch_bounds__(256) void cvt4_kernel(const float* __restrict__ in,
                                                   u16* __restrict__ out, int n) {
  int i = (blockIdx.x * 256 + threadIdx.x) * 4;
  if (i >= n) return;
  float4 v = *(const float4*)(in + i);
  ushort4 o;
  o.x = f2bf(v.x); o.y = f2bf(v.y); o.z = f2bf(v.z); o.w = f2bf(v.w);
  *(ushort4*)(out + i) = o;
}

// out[c][r] = bf16(in[r][c]); R,Cc multiples of 32
__global__ __launch_bounds__(256) void transpose_cvt_kernel(const float* __restrict__ in,
                                                            u16* __restrict__ out,
                                                            int R, int Cc) {
  __shared__ float tile[32][33];
  int c0 = blockIdx.x * 32, r0 = blockIdx.y * 32;
  int tx = threadIdx.x & 31, ty = threadIdx.x >> 5;
#pragma unroll
  for (int rr = ty; rr < 32; rr += 8)
    tile[rr][tx] = in[(size_t)(r0 + rr) * Cc + c0 + tx];
  __syncthreads();
#pragma unroll
  for (int rr = ty; rr < 32; rr += 8)
    out[(size_t)(c0 + rr) * R + r0 + tx] = f2bf(tile[tx][rr]);
}

__global__ __launch_bounds__(256) void decay_init_kernel(float* __restrict__ decay) {
  int d = blockIdx.x * 256 + threadIdx.x;
  if (d >= T_) return;
  float v = 1.0f;
  if (d >= 15) v = 1.0f - powf((float)(d - 15) * (1.0f / 2032.0f), 0.36787944117144233f);
  decay[d] = v;
}

// V [bh][t][d] -> VT [bh][d][t], per-head 64x64 tiles via LDS
__global__ __launch_bounds__(256) void vtrans_kernel(const u16* __restrict__ V,
                                                     u16* __restrict__ VT) {
  __shared__ u16 tile[64][72];
  int bh = blockIdx.y, t0 = blockIdx.x * 64;
  const u16* src = V + ((size_t)bh * T_ + t0) * HD_;
  int r = threadIdx.x >> 2;
  int c8 = (threadIdx.x & 3) * 16;
  *(bf16x8*)(&tile[r][c8])     = *(const bf16x8*)(src + (size_t)r * HD_ + c8);
  *(bf16x8*)(&tile[r][c8 + 8]) = *(const bf16x8*)(src + (size_t)r * HD_ + c8 + 8);
  __syncthreads();
  int d = threadIdx.x >> 2;
  int tc = (threadIdx.x & 3) * 16;
  u16 outv[16];
#pragma unroll
  for (int j = 0; j < 16; ++j) outv[j] = tile[tc + j][d];
  u16* dst = VT + ((size_t)bh * HD_ + d) * T_ + t0 + tc;
  *(bf16x8*)(dst)     = *(bf16x8*)(outv);
  *(bf16x8*)(dst + 8) = *(bf16x8*)(outv + 8);
}

// ---------------- GEMM: C[M][N] = A[M][K] * Bt[N][K]^T ----------------
// 128x128 tile, 4 waves, BK=32, double-buffered LDS, 1 barrier/iter.
template<int MODE>
__global__ __launch_bounds__(256, 3) void gemm128_kernel(
    const u16* __restrict__ A, const u16* __restrict__ Bt,
    float* __restrict__ Cf, u16* __restrict__ Cq, u16* __restrict__ Vt,
    int M, int N, int K)
{
  __shared__ char lds[32768];
  const int lane = threadIdx.x & 63;
  const int wave = threadIdx.x >> 6;
  const int m0 = blockIdx.y << 7;
  const int n0 = blockIdx.x << 7;
  const int wm = wave >> 1, wn = wave & 1;

  f32x4 acc[4][4] = {};

#define GSTAGE(buf, k0)                                                          \
  {                                                                              \
    _Pragma("unroll")                                                            \
    for (int c = 0; c < 2; ++c) {                                                \
      int chunk = wave * 2048 + c * 1024;                                        \
      int row = (chunk >> 6) + (lane >> 2);                                      \
      int wb = ((lane & 3) << 4) ^ ((row & 3) << 4);                             \
      GLD16((const char*)(A  + (size_t)(m0 + row) * K + (k0)) + wb,              \
            lds + (buf) * 16384 + chunk);                                        \
      GLD16((const char*)(Bt + (size_t)(n0 + row) * K + (k0)) + wb,              \
            lds + (buf) * 16384 + 8192 + chunk);                                 \
    }                                                                            \
  }

  GSTAGE(0, 0);
  __syncthreads();

  for (int k0 = 0; k0 < K; k0 += 32) {
    const int cur = (k0 >> 5) & 1;
    if (k0 + 32 < K) GSTAGE(cur ^ 1, k0 + 32);
    const char* base = lds + cur * 16384;
    bf16x8 af[4], bfr[4];
#pragma unroll
    for (int m = 0; m < 4; ++m) {
      int row = wm * 64 + m * 16 + (lane & 15);
      int wb = ((lane >> 4) << 4) ^ ((row & 3) << 4);
      af[m] = *(const bf16x8*)(base + row * 64 + wb);
    }
#pragma unroll
    for (int n = 0; n < 4; ++n) {
      int row = wn * 64 + n * 16 + (lane & 15);
      int wb = ((lane >> 4) << 4) ^ ((row & 3) << 4);
      bfr[n] = *(const bf16x8*)(base + 8192 + row * 64 + wb);
    }
    __builtin_amdgcn_s_setprio(1);
#pragma unroll
    for (int m = 0; m < 4; ++m)
#pragma unroll
      for (int n = 0; n < 4; ++n)
        acc[m][n] = __builtin_amdgcn_mfma_f32_16x16x32_bf16(af[m], bfr[n], acc[m][n], 0, 0, 0);
    __builtin_amdgcn_s_setprio(0);
    __syncthreads();
  }

#pragma unroll
  for (int m = 0; m < 4; ++m) {
    int grow0 = m0 + wm * 64 + m * 16 + ((lane >> 4) << 2);
#pragma unroll
    for (int n = 0; n < 4; ++n) {
      int gcol = n0 + wn * 64 + n * 16 + (lane & 15);
      f32x4 v = acc[m][n];
#pragma unroll
      for (int r = 0; r < 4; ++r) {
        int grow = grow0 + r;
        if (MODE == 0) {
          int bb = grow >> 11, tt = grow & 2047;
          int which = gcol >> 10, rem = gcol & 1023;
          int hh = rem >> 6, dd = rem & 63;
          if (which < 2) {
            float ov = (which == 0) ? v[r] * QSCALE : v[r];
            Cq[((size_t)(which * 32 + bb * 16 + hh) * 2048 + tt) * 64 + dd] = f2bf(ov);
          } else {
            Vt[((size_t)(bb * 16 + hh) * 2048 + tt) * 64 + dd] = f2bf(v[r]);
          }
        } else {
          Cf[(size_t)grow * N + gcol] = v[r];
        }
      }
    }
  }
#undef GSTAGE
}

// ---------------- fused flash attention with post-softmax decay ----------------
// grid (16 tile-pairs, 32 bh); block = 4 waves, each wave owns 16 rows of BOTH
// q-tiles qtA = x and qtB = 31-x  (exactly 33 compute-iters per block -> balanced).
// Shared K/V staging: tiles kt <= qtA feed both q-tiles.
__global__ __launch_bounds__(256, 2) void attn_kernel(
    const u16* __restrict__ qkb, const u16* __restrict__ vtg,
    const float* __restrict__ decayg, u16* __restrict__ yb)
{
  __shared__ char klds[2][8192];   // K tile [64 keys][128B], XOR-swizzled
  __shared__ char vlds[2][8192];   // V^T tile [64 d][128B keys], XOR-swizzled
  __shared__ u16 plds[128 * 76];   // P rows: [0..63] tile B, [64..127] tile A

  const int lane = threadIdx.x & 63;
  const int wave = threadIdx.x >> 6;
  const int quad = lane >> 4;
  const int l15 = lane & 15;
  const int qtA = blockIdx.x;          // 0..15 (short tile)
  const int qtB = 31 - qtA;            // 16..31 (long tile)
  const int bh = blockIdx.y;
  const int b = bh >> 4, h = bh & 15;

  const u16* Q   = qkb + (size_t)bh * T_ * HD_;
  const u16* Kg  = qkb + (size_t)(32 + bh) * T_ * HD_;
  const u16* VTg = vtg + (size_t)bh * HD_ * T_;

  const int wrowB = qtB * 64 + wave * 16;
  const int wrowA = qtA * 64 + wave * 16;
  const int rbB = wrowB + quad * 4;
  const int rbA = wrowA + quad * 4;

  bf16x8 qaB[2], qaA[2];
  { const u16* qp = Q + (size_t)(wrowB + l15) * HD_ + quad * 8;
    qaB[0] = *(const bf16x8*)qp; qaB[1] = *(const bf16x8*)(qp + 32); }
  { const u16* qp = Q + (size_t)(wrowA + l15) * HD_ + quad * 8;
    qaA[0] = *(const bf16x8*)qp; qaA[1] = *(const bf16x8*)(qp + 32); }

  f32x4 accB[4] = {}, accA[4] = {};
  f32x4 lsumB = {}, lsumA = {};

#define ASTAGE(buf, kt)                                                          \
  {                                                                              \
    _Pragma("unroll")                                                            \
    for (int c = 0; c < 2; ++c) {                                                \
      int chunk = wave * 2048 + c * 1024;                                        \
      int row = (chunk >> 7) + (lane >> 3);                                      \
      int wb = ((lane & 7) << 4) ^ ((row & 7) << 4);                             \
      GLD16((const char*)(Kg + (size_t)((kt) * 64 + row) * HD_) + wb,            \
            klds[buf] + chunk);                                                  \
      GLD16((const char*)(VTg + (size_t)row * T_ + (kt) * 64) + wb,              \
            vlds[buf] + chunk);                                                  \
    }                                                                            \
  }

  ASTAGE(0, 0);
  __syncthreads();

  const int nkt = qtB + 1;
  for (int kt = 0; kt < nkt; ++kt) {
    const int cur = kt & 1;
    if (kt + 1 < nkt) ASTAGE(cur ^ 1, kt + 1);
    const bool actA = (kt <= qtA);

    // prefetch decay factors early (VMEM latency hides under the MFMA cluster)
    f32x4 dB[4], dA[4];
#pragma unroll
    for (int f = 0; f < 4; ++f) {
      int key = kt * 64 + f * 16 + l15;
#pragma unroll
      for (int r = 0; r < 4; ++r) {
        int iB = rbB + r - key; iB = iB < 0 ? 0 : iB;
        dB[f][r] = decayg[iB];
      }
    }
    if (actA) {
#pragma unroll
      for (int f = 0; f < 4; ++f) {
        int key = kt * 64 + f * 16 + l15;
#pragma unroll
        for (int r = 0; r < 4; ++r) {
          int iA = rbA + r - key; iA = iA < 0 ? 0 : iA;
          dA[f][r] = decayg[iA];
        }
      }
    }

    // K fragments (read once, shared by both q-tiles)
    bf16x8 kf[4][2];
#pragma unroll
    for (int f = 0; f < 4; ++f) {
      int krow = f * 16 + l15;
      int base = krow * 128;
      int msk = (krow & 7) << 4;
      kf[f][0] = *(const bf16x8*)(klds[cur] + base + ((quad * 16) ^ msk));
      kf[f][1] = *(const bf16x8*)(klds[cur] + base + ((64 + quad * 16) ^ msk));
    }

    // S = Q K^T (log2 domain)
    f32x4 sB[4], sA[4];
    __builtin_amdgcn_s_setprio(1);
#pragma unroll
    for (int f = 0; f < 4; ++f) {
      f32x4 t = {};
      t = __builtin_amdgcn_mfma_f32_16x16x32_bf16(qaB[0], kf[f][0], t, 0, 0, 0);
      t = __builtin_amdgcn_mfma_f32_16x16x32_bf16(qaB[1], kf[f][1], t, 0, 0, 0);
      sB[f] = t;
    }
    if (actA) {
#pragma unroll
      for (int f = 0; f < 4; ++f) {
        f32x4 t = {};
        t = __builtin_amdgcn_mfma_f32_16x16x32_bf16(qaA[0], kf[f][0], t, 0, 0, 0);
        t = __builtin_amdgcn_mfma_f32_16x16x32_bf16(qaA[1], kf[f][1], t, 0, 0, 0);
        sA[f] = t;
      }
    }
    __builtin_amdgcn_s_setprio(0);

    if (kt == qtB) {
#pragma unroll
      for (int f = 0; f < 4; ++f) {
        int key = kt * 64 + f * 16 + l15;
#pragma unroll
        for (int r = 0; r < 4; ++r)
          if (key > rbB + r) sB[f][r] = -1e30f;
      }
    }
    if (actA && kt == qtA) {
#pragma unroll
      for (int f = 0; f < 4; ++f) {
        int key = kt * 64 + f * 16 + l15;
#pragma unroll
        for (int r = 0; r < 4; ++r)
          if (key > rbA + r) sA[f][r] = -1e30f;
      }
    }

    // softmax numerator (with decay) -> plds; denominator (plain) -> lsum
#pragma unroll
    for (int f = 0; f < 4; ++f) {
      f32x4 p;
#pragma unroll
      for (int r = 0; r < 4; ++r) p[r] = EXP2(sB[f][r]);
      lsumB += p;
      u16* pw = plds + (size_t)(wave * 16 + quad * 4) * 76 + l15 + f * 16;
#pragma unroll
      for (int r = 0; r < 4; ++r)
        pw[(size_t)r * 76] = f2bf(p[r] * dB[f][r]);
    }
    if (actA) {
#pragma unroll
      for (int f = 0; f < 4; ++f) {
        f32x4 p;
#pragma unroll
        for (int r = 0; r < 4; ++r) p[r] = EXP2(sA[f][r]);
        lsumA += p;
        u16* pw = plds + (size_t)(64 + wave * 16 + quad * 4) * 76 + l15 + f * 16;
#pragma unroll
        for (int r = 0; r < 4; ++r)
          pw[(size_t)r * 76] = f2bf(p[r] * dA[f][r]);
      }
    }

    // V fragments (read once, shared)
    bf16x8 vf[4][2];
#pragma unroll
    for (int n = 0; n < 4; ++n) {
      int vrow = n * 16 + l15;
      int mskv = (vrow & 7) << 4;
#pragma unroll
      for (int ks = 0; ks < 2; ++ks)
        vf[n][ks] = *(const bf16x8*)(vlds[cur] + vrow * 128 + ((ks * 64 + quad * 16) ^ mskv));
    }

    // y += P @ V
    __builtin_amdgcn_s_setprio(1);
#pragma unroll
    for (int ks = 0; ks < 2; ++ks) {
      bf16x8 pa = *(const bf16x8*)(plds + (size_t)(wave * 16 + l15) * 76 + ks * 32 + quad * 8);
#pragma unroll
      for (int n = 0; n < 4; ++n)
        accB[n] = __builtin_amdgcn_mfma_f32_16x16x32_bf16(pa, vf[n][ks], accB[n], 0, 0, 0);
    }
    if (actA) {
#pragma unroll
      for (int ks = 0; ks < 2; ++ks) {
        bf16x8 pa = *(const bf16x8*)(plds + (size_t)(64 + wave * 16 + l15) * 76 + ks * 32 + quad * 8);
#pragma unroll
        for (int n = 0; n < 4; ++n)
          accA[n] = __builtin_amdgcn_mfma_f32_16x16x32_bf16(pa, vf[n][ks], accA[n], 0, 0, 0);
      }
    }
    __builtin_amdgcn_s_setprio(0);
    __syncthreads();   // drains vmcnt(0): next buffer staged, everyone done with cur
  }
#undef ASTAGE

  // finalize both tiles
  f32x4 liB = lsumB, liA = lsumA;
#pragma unroll
  for (int d = 1; d < 16; d <<= 1) {
#pragma unroll
    for (int r = 0; r < 4; ++r) {
      liB[r] += __shfl_xor(liB[r], d);
      liA[r] += __shfl_xor(liA[r], d);
    }
  }
#pragma unroll
  for (int n = 0; n < 4; ++n) {
    int d = h * 64 + n * 16 + l15;
#pragma unroll
    for (int r = 0; r < 4; ++r) {
      int tB = wrowB + quad * 4 + r;
      int tA = wrowA + quad * 4 + r;
      yb[((size_t)b * T_ + tB) * 1024 + d] = f2bf(accB[n][r] / liB[r]);
      yb[((size_t)b * T_ + tA) * 1024 + d] = f2bf(accA[n][r] / liA[r]);
    }
  }
}

// ---------------- launch ----------------
extern "C" void kernel_launch(void* const* d_in, const int* in_sizes, int n_in,
                              void* d_out, int out_size, void* d_ws, size_t ws_size,
                              hipStream_t stream) {
  const float* x  = (const float*)d_in[0];
  const float* Wa = (const float*)d_in[1];
  const float* Wp = (const float*)d_in[2];
  float* out = (float*)d_out;
  char* ws = (char*)d_ws;

  // workspace layout (bytes), total 50,339,840
  u16*   xb    = (u16*)(ws + 0);           //  8,388,608  x bf16; reused as yb
  u16*   WaT   = (u16*)(ws + 8388608);     //  6,291,456  W_attn^T bf16
  u16*   WpT   = (u16*)(ws + 14680064);    //  2,097,152  W_proj^T bf16
  u16*   qkb   = (u16*)(ws + 16777216);    // 16,777,216  Q,K bf16 [2][32][2048][64]
  u16*   Vtmp  = (u16*)(ws + 33554432);    //  8,388,608  V bf16 [32][2048][64]
  u16*   VT    = (u16*)(ws + 41943040);    //  8,388,608  V^T bf16 [32][64][2048]
  float* decay = (float*)(ws + 50331648);  //      8,192  decay table f32[2048]
  u16*   yb    = xb;

  cvt4_kernel<<<4096, 256, 0, stream>>>(x, xb, B_ * T_ * C_);
  transpose_cvt_kernel<<<dim3(96, 32), 256, 0, stream>>>(Wa, WaT, C_, N3_);
  transpose_cvt_kernel<<<dim3(32, 32), 256, 0, stream>>>(Wp, WpT, C_, C_);
  decay_init_kernel<<<8, 256, 0, stream>>>(decay);

  gemm128_kernel<0><<<dim3(N3_ / 128, 32), 256, 0, stream>>>(
      xb, WaT, nullptr, qkb, Vtmp, B_ * T_, N3_, C_);
  vtrans_kernel<<<dim3(32, 32), 256, 0, stream>>>(Vtmp, VT);
  attn_kernel<<<dim3(16, 32), 256, 0, stream>>>(qkb, VT, decay, yb);
  gemm128_kernel<1><<<dim3(1024 / 128, 32), 256, 0, stream>>>(
      yb, WpT, out, nullptr, nullptr, B_ * T_, 1024, 1024);
}

// Round 5
// 121.750 us; speedup vs baseline: 1.8143x; 1.0688x over previous
//
#include <hip/hip_runtime.h>
#include <math.h>

// ws footprint: 50,331,648 bytes used (decay table lives in dead Vtmp region).
#define B_  2
#define T_  2048
#define C_  1024
#define NH_ 16
#define HD_ 64
#define N3_ 3072

typedef float f32x4 __attribute__((ext_vector_type(4)));
typedef short bf16x8 __attribute__((ext_vector_type(8)));
typedef unsigned short u16;

// Q prescale: 1/sqrt(64) * log2(e), so softmax uses exp2 directly.
#define QSCALE 0.18033688011112042f

#if __has_builtin(__builtin_amdgcn_exp2f)
#define EXP2(x) __builtin_amdgcn_exp2f(x)
#else
#define EXP2(x) exp2f(x)
#endif

__device__ __forceinline__ u16 f2bf(float x) {
  unsigned int u = __builtin_bit_cast(unsigned int, x);
  u += 0x7FFFu + ((u >> 16) & 1u);
  return (u16)(u >> 16);
}

__device__ __forceinline__ unsigned int cvt_pk_bf16(float lo, float hi) {
  unsigned int r;
  asm("v_cvt_pk_bf16_f32 %0, %1, %2" : "=v"(r) : "v"(lo), "v"(hi));
  return r;
}

#define GLD16(g, l) __builtin_amdgcn_global_load_lds( \
    (__attribute__((address_space(1))) void*)(g), \
    (__attribute__((address_space(3))) void*)(l), 16, 0, 0)

// ---------------- converts ----------------
__global__ __launch_bounds__(256) void cvt4_kernel(const float* __restrict__ in,
                                                   u16* __restrict__ out, int n) {
  int i = (blockIdx.x * 256 + threadIdx.x) * 4;
  if (i >= n) return;
  float4 v = *(const float4*)(in + i);
  ushort4 o;
  o.x = f2bf(v.x); o.y = f2bf(v.y); o.z = f2bf(v.z); o.w = f2bf(v.w);
  *(ushort4*)(out + i) = o;
}

// out[c][r] = bf16(in[r][c]); R,Cc multiples of 32
__global__ __launch_bounds__(256) void transpose_cvt_kernel(const float* __restrict__ in,
                                                            u16* __restrict__ out,
                                                            int R, int Cc) {
  __shared__ float tile[32][33];
  int c0 = blockIdx.x * 32, r0 = blockIdx.y * 32;
  int tx = threadIdx.x & 31, ty = threadIdx.x >> 5;
#pragma unroll
  for (int rr = ty; rr < 32; rr += 8)
    tile[rr][tx] = in[(size_t)(r0 + rr) * Cc + c0 + tx];
  __syncthreads();
#pragma unroll
  for (int rr = ty; rr < 32; rr += 8)
    out[(size_t)(c0 + rr) * R + r0 + tx] = f2bf(tile[tx][rr]);
}

// decayp[0..127] = pad (1.0, only multiplied by p==0), decayp[128+d] = decay(d)
__global__ __launch_bounds__(256) void decay_init_kernel(float* __restrict__ decayp) {
  int i = blockIdx.x * 256 + threadIdx.x;
  if (i >= 2176) return;
  int d = i - 128;
  float v = 1.0f;
  if (d >= 15) v = 1.0f - powf((float)(d - 15) * (1.0f / 2032.0f), 0.36787944117144233f);
  decayp[i] = v;
}

// V [bh][t][d] -> VT [bh][d][t], per-head 64x64 tiles via LDS
__global__ __launch_bounds__(256) void vtrans_kernel(const u16* __restrict__ V,
                                                     u16* __restrict__ VT) {
  __shared__ u16 tile[64][72];
  int bh = blockIdx.y, t0 = blockIdx.x * 64;
  const u16* src = V + ((size_t)bh * T_ + t0) * HD_;
  int r = threadIdx.x >> 2;
  int c8 = (threadIdx.x & 3) * 16;
  *(bf16x8*)(&tile[r][c8])     = *(const bf16x8*)(src + (size_t)r * HD_ + c8);
  *(bf16x8*)(&tile[r][c8 + 8]) = *(const bf16x8*)(src + (size_t)r * HD_ + c8 + 8);
  __syncthreads();
  int d = threadIdx.x >> 2;
  int tc = (threadIdx.x & 3) * 16;
  u16 outv[16];
#pragma unroll
  for (int j = 0; j < 16; ++j) outv[j] = tile[tc + j][d];
  u16* dst = VT + ((size_t)bh * HD_ + d) * T_ + t0 + tc;
  *(bf16x8*)(dst)     = *(bf16x8*)(outv);
  *(bf16x8*)(dst + 8) = *(bf16x8*)(outv + 8);
}

// ---------------- GEMM: C[M][N] = A[M][K] * Bt[N][K]^T ----------------
// 128x128 tile, 4 waves, BK=32, double-buffered LDS, 1 barrier/iter.
template<int MODE>
__global__ __launch_bounds__(256, 3) void gemm128_kernel(
    const u16* __restrict__ A, const u16* __restrict__ Bt,
    float* __restrict__ Cf, u16* __restrict__ Cq, u16* __restrict__ Vt,
    int M, int N, int K)
{
  __shared__ char lds[32768];
  const int lane = threadIdx.x & 63;
  const int wave = threadIdx.x >> 6;
  const int m0 = blockIdx.y << 7;
  const int n0 = blockIdx.x << 7;
  const int wm = wave >> 1, wn = wave & 1;

  f32x4 acc[4][4] = {};

#define GSTAGE(buf, k0)                                                          \
  {                                                                              \
    _Pragma("unroll")                                                            \
    for (int c = 0; c < 2; ++c) {                                                \
      int chunk = wave * 2048 + c * 1024;                                        \
      int row = (chunk >> 6) + (lane >> 2);                                      \
      int wb = ((lane & 3) << 4) ^ ((row & 3) << 4);                             \
      GLD16((const char*)(A  + (size_t)(m0 + row) * K + (k0)) + wb,              \
            lds + (buf) * 16384 + chunk);                                        \
      GLD16((const char*)(Bt + (size_t)(n0 + row) * K + (k0)) + wb,              \
            lds + (buf) * 16384 + 8192 + chunk);                                 \
    }                                                                            \
  }

  GSTAGE(0, 0);
  __syncthreads();

  for (int k0 = 0; k0 < K; k0 += 32) {
    const int cur = (k0 >> 5) & 1;
    if (k0 + 32 < K) GSTAGE(cur ^ 1, k0 + 32);
    const char* base = lds + cur * 16384;
    bf16x8 af[4], bfr[4];
#pragma unroll
    for (int m = 0; m < 4; ++m) {
      int row = wm * 64 + m * 16 + (lane & 15);
      int wb = ((lane >> 4) << 4) ^ ((row & 3) << 4);
      af[m] = *(const bf16x8*)(base + row * 64 + wb);
    }
#pragma unroll
    for (int n = 0; n < 4; ++n) {
      int row = wn * 64 + n * 16 + (lane & 15);
      int wb = ((lane >> 4) << 4) ^ ((row & 3) << 4);
      bfr[n] = *(const bf16x8*)(base + 8192 + row * 64 + wb);
    }
    __builtin_amdgcn_s_setprio(1);
#pragma unroll
    for (int m = 0; m < 4; ++m)
#pragma unroll
      for (int n = 0; n < 4; ++n)
        acc[m][n] = __builtin_amdgcn_mfma_f32_16x16x32_bf16(af[m], bfr[n], acc[m][n], 0, 0, 0);
    __builtin_amdgcn_s_setprio(0);
    __syncthreads();
  }

#pragma unroll
  for (int m = 0; m < 4; ++m) {
    int grow0 = m0 + wm * 64 + m * 16 + ((lane >> 4) << 2);
#pragma unroll
    for (int n = 0; n < 4; ++n) {
      int gcol = n0 + wn * 64 + n * 16 + (lane & 15);
      f32x4 v = acc[m][n];
#pragma unroll
      for (int r = 0; r < 4; ++r) {
        int grow = grow0 + r;
        if (MODE == 0) {
          int bb = grow >> 11, tt = grow & 2047;
          int which = gcol >> 10, rem = gcol & 1023;
          int hh = rem >> 6, dd = rem & 63;
          if (which < 2) {
            float ov = (which == 0) ? v[r] * QSCALE : v[r];
            Cq[((size_t)(which * 32 + bb * 16 + hh) * 2048 + tt) * 64 + dd] = f2bf(ov);
          } else {
            Vt[((size_t)(bb * 16 + hh) * 2048 + tt) * 64 + dd] = f2bf(v[r]);
          }
        } else {
          Cf[(size_t)grow * N + gcol] = v[r];
        }
      }
    }
  }
#undef GSTAGE
}

// ---------------- fused flash attention with post-softmax decay ----------------
// grid (16 tile-pairs, 32 bh); block = 4 waves; wave owns 16 rows of q-tiles
// qtA = x (short) and qtB = 31-x (long): exactly 33 compute-iters per block.
// QK^T computed TRANSPOSED (mfma(K,Q)): S^T col=q=lane&15, row=key=quad*4+r ->
// keys are lane-local/consecutive: vectorized P-writes (b64), cvt_pk packing,
// offset-folded decay loads from a padded table, scalar per-lane denominator.
__global__ __launch_bounds__(256, 2) void attn_kernel(
    const u16* __restrict__ qkb, const u16* __restrict__ vtg,
    const float* __restrict__ decayg,   // = decayp + 128 (padded below)
    u16* __restrict__ yb)
{
  __shared__ char klds[2][8192];   // K tile [64 keys][128B], XOR-swizzled
  __shared__ char vlds[2][8192];   // V^T tile [64 d][128B keys], XOR-swizzled
  __shared__ u16 plds[128 * 76];   // P [q][key]: rows 0..63 tile B, 64..127 tile A

  const int lane = threadIdx.x & 63;
  const int wave = threadIdx.x >> 6;
  const int quad = lane >> 4;
  const int l15 = lane & 15;
  const int qtA = blockIdx.x;          // 0..15 (short tile)
  const int qtB = 31 - qtA;            // 16..31 (long tile)
  const int bh = blockIdx.y;
  const int b = bh >> 4, h = bh & 15;

  const u16* Q   = qkb + (size_t)bh * T_ * HD_;
  const u16* Kg  = qkb + (size_t)(32 + bh) * T_ * HD_;
  const u16* VTg = vtg + (size_t)bh * HD_ * T_;

  const int wrowB = qtB * 64 + wave * 16;
  const int wrowA = qtA * 64 + wave * 16;
  const int qB = wrowB + l15;          // this lane's S^T column (global q), tile B
  const int qA = wrowA + l15;
  const int qBq = qB - quad * 4;       // decay base helpers
  const int qAq = qA - quad * 4;

  bf16x8 qaB[2], qaA[2];
  { const u16* qp = Q + (size_t)(wrowB + l15) * HD_ + quad * 8;
    qaB[0] = *(const bf16x8*)qp; qaB[1] = *(const bf16x8*)(qp + 32); }
  { const u16* qp = Q + (size_t)(wrowA + l15) * HD_ + quad * 8;
    qaA[0] = *(const bf16x8*)qp; qaA[1] = *(const bf16x8*)(qp + 32); }

  f32x4 accB[4] = {}, accA[4] = {};
  float lsumB = 0.0f, lsumA = 0.0f;

#define ASTAGE(buf, kt)                                                          \
  {                                                                              \
    _Pragma("unroll")                                                            \
    for (int c = 0; c < 2; ++c) {                                                \
      int chunk = wave * 2048 + c * 1024;                                        \
      int row = (chunk >> 7) + (lane >> 3);                                      \
      int wb = ((lane & 7) << 4) ^ ((row & 7) << 4);                             \
      GLD16((const char*)(Kg + (size_t)((kt) * 64 + row) * HD_) + wb,            \
            klds[buf] + chunk);                                                  \
      GLD16((const char*)(VTg + (size_t)row * T_ + (kt) * 64) + wb,              \
            vlds[buf] + chunk);                                                  \
    }                                                                            \
  }

  ASTAGE(0, 0);
  __syncthreads();

  const int nkt = qtB + 1;
  for (int kt = 0; kt < nkt; ++kt) {
    const int cur = kt & 1;
    if (kt + 1 < nkt) ASTAGE(cur ^ 1, kt + 1);
    const bool actA = (kt <= qtA);

    // K fragments (read once, shared by both q-tiles)
    bf16x8 kf[4][2];
#pragma unroll
    for (int f = 0; f < 4; ++f) {
      int krow = f * 16 + l15;
      int base = krow * 128;
      int msk = (krow & 7) << 4;
      kf[f][0] = *(const bf16x8*)(klds[cur] + base + ((quad * 16) ^ msk));
      kf[f][1] = *(const bf16x8*)(klds[cur] + base + ((64 + quad * 16) ^ msk));
    }

    // S^T = K Q^T (log2 domain): col=q=l15, row=key=f*16+quad*4+r
    f32x4 sB[4], sA[4];
    __builtin_amdgcn_s_setprio(1);
#pragma unroll
    for (int f = 0; f < 4; ++f) {
      f32x4 t = {};
      t = __builtin_amdgcn_mfma_f32_16x16x32_bf16(kf[f][0], qaB[0], t, 0, 0, 0);
      t = __builtin_amdgcn_mfma_f32_16x16x32_bf16(kf[f][1], qaB[1], t, 0, 0, 0);
      sB[f] = t;
    }
    if (actA) {
#pragma unroll
      for (int f = 0; f < 4; ++f) {
        f32x4 t = {};
        t = __builtin_amdgcn_mfma_f32_16x16x32_bf16(kf[f][0], qaA[0], t, 0, 0, 0);
        t = __builtin_amdgcn_mfma_f32_16x16x32_bf16(kf[f][1], qaA[1], t, 0, 0, 0);
        sA[f] = t;
      }
    }
    __builtin_amdgcn_s_setprio(0);

    if (kt == qtB) {   // diagonal: mask key > q
#pragma unroll
      for (int f = 0; f < 4; ++f) {
        int key0 = kt * 64 + f * 16 + quad * 4;
#pragma unroll
        for (int r = 0; r < 4; ++r)
          if (key0 + r > qB) sB[f][r] = -1e30f;
      }
    }
    if (actA && kt == qtA) {
#pragma unroll
      for (int f = 0; f < 4; ++f) {
        int key0 = kt * 64 + f * 16 + quad * 4;
#pragma unroll
        for (int r = 0; r < 4; ++r)
          if (key0 + r > qA) sA[f][r] = -1e30f;
      }
    }

    // softmax: denom = sum exp2(s); numerator = exp2(s)*decay -> packed bf16
    {
      const float* db = decayg + (qBq - kt * 64);   // db[-(f*16)-r] = decay idx
#pragma unroll
      for (int f = 0; f < 4; ++f) {
        f32x4 p;
#pragma unroll
        for (int r = 0; r < 4; ++r) p[r] = EXP2(sB[f][r]);
        lsumB += (p[0] + p[1]) + (p[2] + p[3]);
        const float* dbf = db - f * 16;
        unsigned int w0 = cvt_pk_bf16(p[0] * dbf[0],  p[1] * dbf[-1]);
        unsigned int w1 = cvt_pk_bf16(p[2] * dbf[-2], p[3] * dbf[-3]);
        uint2 wv; wv.x = w0; wv.y = w1;
        *(uint2*)(plds + (size_t)(wave * 16 + l15) * 76 + f * 16 + quad * 4) = wv;
      }
    }
    if (actA) {
      const float* db = decayg + (qAq - kt * 64);
#pragma unroll
      for (int f = 0; f < 4; ++f) {
        f32x4 p;
#pragma unroll
        for (int r = 0; r < 4; ++r) p[r] = EXP2(sA[f][r]);
        lsumA += (p[0] + p[1]) + (p[2] + p[3]);
        const float* dbf = db - f * 16;
        unsigned int w0 = cvt_pk_bf16(p[0] * dbf[0],  p[1] * dbf[-1]);
        unsigned int w1 = cvt_pk_bf16(p[2] * dbf[-2], p[3] * dbf[-3]);
        uint2 wv; wv.x = w0; wv.y = w1;
        *(uint2*)(plds + (size_t)(64 + wave * 16 + l15) * 76 + f * 16 + quad * 4) = wv;
      }
    }

    // V fragments (read once, shared)
    bf16x8 vf[4][2];
#pragma unroll
    for (int n = 0; n < 4; ++n) {
      int vrow = n * 16 + l15;
      int mskv = (vrow & 7) << 4;
#pragma unroll
      for (int ks = 0; ks < 2; ++ks)
        vf[n][ks] = *(const bf16x8*)(vlds[cur] + vrow * 128 + ((ks * 64 + quad * 16) ^ mskv));
    }

    // y += P @ V
    __builtin_amdgcn_s_setprio(1);
#pragma unroll
    for (int ks = 0; ks < 2; ++ks) {
      bf16x8 pa = *(const bf16x8*)(plds + (size_t)(wave * 16 + l15) * 76 + ks * 32 + quad * 8);
#pragma unroll
      for (int n = 0; n < 4; ++n)
        accB[n] = __builtin_amdgcn_mfma_f32_16x16x32_bf16(pa, vf[n][ks], accB[n], 0, 0, 0);
    }
    if (actA) {
#pragma unroll
      for (int ks = 0; ks < 2; ++ks) {
        bf16x8 pa = *(const bf16x8*)(plds + (size_t)(64 + wave * 16 + l15) * 76 + ks * 32 + quad * 8);
#pragma unroll
        for (int n = 0; n < 4; ++n)
          accA[n] = __builtin_amdgcn_mfma_f32_16x16x32_bf16(pa, vf[n][ks], accA[n], 0, 0, 0);
      }
    }
    __builtin_amdgcn_s_setprio(0);
    __syncthreads();   // drains vmcnt(0): next buffer staged, everyone done with cur
  }
#undef ASTAGE

  // finalize: denom for q=l15 -> reduce across quads, broadcast to q=quad*4+r
  lsumB += __shfl_xor(lsumB, 16); lsumB += __shfl_xor(lsumB, 32);
  lsumA += __shfl_xor(lsumA, 16); lsumA += __shfl_xor(lsumA, 32);
  float rB[4], rA[4];
#pragma unroll
  for (int r = 0; r < 4; ++r) {
    rB[r] = 1.0f / __shfl(lsumB, quad * 4 + r, 16);
    rA[r] = 1.0f / __shfl(lsumA, quad * 4 + r, 16);
  }
#pragma unroll
  for (int n = 0; n < 4; ++n) {
    int d = h * 64 + n * 16 + l15;
#pragma unroll
    for (int r = 0; r < 4; ++r) {
      int tB = wrowB + quad * 4 + r;
      int tA = wrowA + quad * 4 + r;
      yb[((size_t)b * T_ + tB) * 1024 + d] = f2bf(accB[n][r] * rB[r]);
      yb[((size_t)b * T_ + tA) * 1024 + d] = f2bf(accA[n][r] * rA[r]);
    }
  }
}

// ---------------- launch ----------------
extern "C" void kernel_launch(void* const* d_in, const int* in_sizes, int n_in,
                              void* d_out, int out_size, void* d_ws, size_t ws_size,
                              hipStream_t stream) {
  const float* x  = (const float*)d_in[0];
  const float* Wa = (const float*)d_in[1];
  const float* Wp = (const float*)d_in[2];
  float* out = (float*)d_out;
  char* ws = (char*)d_ws;

  // workspace layout (bytes), total 50,331,648
  u16*   xb    = (u16*)(ws + 0);           //  8,388,608  x bf16; reused as yb
  u16*   WaT   = (u16*)(ws + 8388608);     //  6,291,456  W_attn^T bf16
  u16*   WpT   = (u16*)(ws + 14680064);    //  2,097,152  W_proj^T bf16
  u16*   qkb   = (u16*)(ws + 16777216);    // 16,777,216  Q,K bf16 [2][32][2048][64]
  u16*   Vtmp  = (u16*)(ws + 33554432);    //  8,388,608  V bf16 (dead after vtrans;
                                           //             head reused for decay table)
  u16*   VT    = (u16*)(ws + 41943040);    //  8,388,608  V^T bf16 [32][64][2048]
  float* decayp = (float*)Vtmp;            //  8,704 B    padded decay table
  u16*   yb    = xb;

  cvt4_kernel<<<4096, 256, 0, stream>>>(x, xb, B_ * T_ * C_);
  transpose_cvt_kernel<<<dim3(96, 32), 256, 0, stream>>>(Wa, WaT, C_, N3_);
  transpose_cvt_kernel<<<dim3(32, 32), 256, 0, stream>>>(Wp, WpT, C_, C_);

  gemm128_kernel<0><<<dim3(N3_ / 128, 32), 256, 0, stream>>>(
      xb, WaT, nullptr, qkb, Vtmp, B_ * T_, N3_, C_);
  vtrans_kernel<<<dim3(32, 32), 256, 0, stream>>>(Vtmp, VT);
  decay_init_kernel<<<9, 256, 0, stream>>>(decayp);   // after vtrans: overwrites Vtmp head
  attn_kernel<<<dim3(16, 32), 256, 0, stream>>>(qkb, VT, decayp + 128, yb);
  gemm128_kernel<1><<<dim3(1024 / 128, 32), 256, 0, stream>>>(
      yb, WpT, out, nullptr, nullptr, B_ * T_, 1024, 1024);
}

// Round 6
// 120.733 us; speedup vs baseline: 1.8296x; 1.0084x over previous
//
#include <hip/hip_runtime.h>
#include <math.h>

// ws footprint: 50,331,648 bytes used (decay table lives in dead Vtmp region).
#define B_  2
#define T_  2048
#define C_  1024
#define NH_ 16
#define HD_ 64
#define N3_ 3072

typedef float f32x4 __attribute__((ext_vector_type(4)));
typedef short bf16x8 __attribute__((ext_vector_type(8)));
typedef unsigned short u16;
typedef float f32x4_base __attribute__((ext_vector_type(4)));
typedef f32x4_base __attribute__((aligned(4))) f32x4u;   // 4B-aligned vector load

// Q prescale: 1/sqrt(64) * log2(e), so softmax uses exp2 directly.
#define QSCALE 0.18033688011112042f

#if __has_builtin(__builtin_amdgcn_exp2f)
#define EXP2(x) __builtin_amdgcn_exp2f(x)
#else
#define EXP2(x) exp2f(x)
#endif

__device__ __forceinline__ u16 f2bf(float x) {
  unsigned int u = __builtin_bit_cast(unsigned int, x);
  u += 0x7FFFu + ((u >> 16) & 1u);
  return (u16)(u >> 16);
}

__device__ __forceinline__ unsigned int cvt_pk_bf16(float lo, float hi) {
  unsigned int r;
  asm("v_cvt_pk_bf16_f32 %0, %1, %2" : "=v"(r) : "v"(lo), "v"(hi));
  return r;
}

#define GLD16(g, l) __builtin_amdgcn_global_load_lds( \
    (__attribute__((address_space(1))) void*)(g), \
    (__attribute__((address_space(3))) void*)(l), 16, 0, 0)

// ---------------- converts ----------------
__global__ __launch_bounds__(256) void cvt4_kernel(const float* __restrict__ in,
                                                   u16* __restrict__ out, int n) {
  int i = (blockIdx.x * 256 + threadIdx.x) * 4;
  if (i >= n) return;
  float4 v = *(const float4*)(in + i);
  ushort4 o;
  o.x = f2bf(v.x); o.y = f2bf(v.y); o.z = f2bf(v.z); o.w = f2bf(v.w);
  *(ushort4*)(out + i) = o;
}

// out[c][r] = bf16(in[r][c]); R,Cc multiples of 32
__global__ __launch_bounds__(256) void transpose_cvt_kernel(const float* __restrict__ in,
                                                            u16* __restrict__ out,
                                                            int R, int Cc) {
  __shared__ float tile[32][33];
  int c0 = blockIdx.x * 32, r0 = blockIdx.y * 32;
  int tx = threadIdx.x & 31, ty = threadIdx.x >> 5;
#pragma unroll
  for (int rr = ty; rr < 32; rr += 8)
    tile[rr][tx] = in[(size_t)(r0 + rr) * Cc + c0 + tx];
  __syncthreads();
#pragma unroll
  for (int rr = ty; rr < 32; rr += 8)
    out[(size_t)(c0 + rr) * R + r0 + tx] = f2bf(tile[tx][rr]);
}

// Reversed + padded decay table: decR[j] = decay(2047-j) for j<=2047, 1.0 above
// (pad entries are only ever multiplied by p==0 in the masked region).
__global__ __launch_bounds__(256) void decay_init_kernel(float* __restrict__ decR) {
  int j = blockIdx.x * 256 + threadIdx.x;
  if (j >= 2176) return;
  int d = 2047 - j;
  float v = 1.0f;
  if (d >= 15) v = 1.0f - powf((float)(d - 15) * (1.0f / 2032.0f), 0.36787944117144233f);
  decR[j] = v;   // d < 15 (incl. negative pad) -> 1.0
}

// V [bh][t][d] -> VT [bh][d][t], per-head 64x64 tiles via LDS
__global__ __launch_bounds__(256) void vtrans_kernel(const u16* __restrict__ V,
                                                     u16* __restrict__ VT) {
  __shared__ u16 tile[64][72];
  int bh = blockIdx.y, t0 = blockIdx.x * 64;
  const u16* src = V + ((size_t)bh * T_ + t0) * HD_;
  int r = threadIdx.x >> 2;
  int c8 = (threadIdx.x & 3) * 16;
  *(bf16x8*)(&tile[r][c8])     = *(const bf16x8*)(src + (size_t)r * HD_ + c8);
  *(bf16x8*)(&tile[r][c8 + 8]) = *(const bf16x8*)(src + (size_t)r * HD_ + c8 + 8);
  __syncthreads();
  int d = threadIdx.x >> 2;
  int tc = (threadIdx.x & 3) * 16;
  u16 outv[16];
#pragma unroll
  for (int j = 0; j < 16; ++j) outv[j] = tile[tc + j][d];
  u16* dst = VT + ((size_t)bh * HD_ + d) * T_ + t0 + tc;
  *(bf16x8*)(dst)     = *(bf16x8*)(outv);
  *(bf16x8*)(dst + 8) = *(bf16x8*)(outv + 8);
}

// ---------------- GEMM: C[M][N] = A[M][K] * Bt[N][K]^T ----------------
// 128x128 tile, 4 waves, BK=32, double-buffered LDS, 1 barrier/iter.
// Flattened grid with bijective XCD-chunk swizzle (grid %8 == 0).
template<int MODE>
__global__ __launch_bounds__(256, 3) void gemm128_kernel(
    const u16* __restrict__ A, const u16* __restrict__ Bt,
    float* __restrict__ Cf, u16* __restrict__ Cq, u16* __restrict__ Vt,
    int M, int N, int K)
{
  __shared__ char lds[32768];
  const int lane = threadIdx.x & 63;
  const int wave = threadIdx.x >> 6;
  const int nxb = N >> 7;
  const int orig = blockIdx.x;
  const int cpx = (int)gridDim.x >> 3;
  const int wg = (orig & 7) * cpx + (orig >> 3);
  const int m0 = (wg / nxb) << 7;
  const int n0 = (wg % nxb) << 7;
  const int wm = wave >> 1, wn = wave & 1;

  f32x4 acc[4][4] = {};

#define GSTAGE(buf, k0)                                                          \
  {                                                                              \
    _Pragma("unroll")                                                            \
    for (int c = 0; c < 2; ++c) {                                                \
      int chunk = wave * 2048 + c * 1024;                                        \
      int row = (chunk >> 6) + (lane >> 2);                                      \
      int wb = ((lane & 3) << 4) ^ ((row & 3) << 4);                             \
      GLD16((const char*)(A  + (size_t)(m0 + row) * K + (k0)) + wb,              \
            lds + (buf) * 16384 + chunk);                                        \
      GLD16((const char*)(Bt + (size_t)(n0 + row) * K + (k0)) + wb,              \
            lds + (buf) * 16384 + 8192 + chunk);                                 \
    }                                                                            \
  }

  GSTAGE(0, 0);
  __syncthreads();

  for (int k0 = 0; k0 < K; k0 += 32) {
    const int cur = (k0 >> 5) & 1;
    if (k0 + 32 < K) GSTAGE(cur ^ 1, k0 + 32);
    const char* base = lds + cur * 16384;
    bf16x8 af[4], bfr[4];
#pragma unroll
    for (int m = 0; m < 4; ++m) {
      int row = wm * 64 + m * 16 + (lane & 15);
      int wb = ((lane >> 4) << 4) ^ ((row & 3) << 4);
      af[m] = *(const bf16x8*)(base + row * 64 + wb);
    }
#pragma unroll
    for (int n = 0; n < 4; ++n) {
      int row = wn * 64 + n * 16 + (lane & 15);
      int wb = ((lane >> 4) << 4) ^ ((row & 3) << 4);
      bfr[n] = *(const bf16x8*)(base + 8192 + row * 64 + wb);
    }
    __builtin_amdgcn_s_setprio(1);
#pragma unroll
    for (int m = 0; m < 4; ++m)
#pragma unroll
      for (int n = 0; n < 4; ++n)
        acc[m][n] = __builtin_amdgcn_mfma_f32_16x16x32_bf16(af[m], bfr[n], acc[m][n], 0, 0, 0);
    __builtin_amdgcn_s_setprio(0);
    __syncthreads();
  }

#pragma unroll
  for (int m = 0; m < 4; ++m) {
    int grow0 = m0 + wm * 64 + m * 16 + ((lane >> 4) << 2);
#pragma unroll
    for (int n = 0; n < 4; ++n) {
      int gcol = n0 + wn * 64 + n * 16 + (lane & 15);
      f32x4 v = acc[m][n];
#pragma unroll
      for (int r = 0; r < 4; ++r) {
        int grow = grow0 + r;
        if (MODE == 0) {
          int bb = grow >> 11, tt = grow & 2047;
          int which = gcol >> 10, rem = gcol & 1023;
          int hh = rem >> 6, dd = rem & 63;
          if (which < 2) {
            float ov = (which == 0) ? v[r] * QSCALE : v[r];
            Cq[((size_t)(which * 32 + bb * 16 + hh) * 2048 + tt) * 64 + dd] = f2bf(ov);
          } else {
            Vt[((size_t)(bb * 16 + hh) * 2048 + tt) * 64 + dd] = f2bf(v[r]);
          }
        } else {
          Cf[(size_t)grow * N + gcol] = v[r];
        }
      }
    }
  }
#undef GSTAGE
}

// ---------------- fused flash attention with post-softmax decay ----------------
// flat grid 512, XCD-chunk swizzled; block = 4 waves; wave owns 16 rows of
// q-tiles qtA (short) and qtB=31-qtA (long): exactly 33 compute-iters/block.
// S^T = mfma(K,Q): col=q=lane&15, row=key=quad*4+r -> keys lane-local.
// Decay factors come from the reversed table as one dwordx4 per f-block.
__global__ __launch_bounds__(256, 3) void attn_kernel(
    const u16* __restrict__ qkb, const u16* __restrict__ vtg,
    const float* __restrict__ decR, u16* __restrict__ yb)
{
  __shared__ char klds[2][8192];   // K tile [64 keys][128B], XOR-swizzled
  __shared__ char vlds[2][8192];   // V^T tile [64 d][128B keys], XOR-swizzled
  __shared__ u16 plds[128 * 76];   // P [q][key]: rows 0..63 tile B, 64..127 tile A

  const int lane = threadIdx.x & 63;
  const int wave = threadIdx.x >> 6;
  const int quad = lane >> 4;
  const int l15 = lane & 15;
  const int orig = blockIdx.x;
  const int wg = ((orig & 7) << 6) + (orig >> 3);   // 64 blocks (4 bh) per XCD
  const int qtA = wg & 15;             // 0..15 (short tile)
  const int qtB = 31 - qtA;            // 16..31 (long tile)
  const int bh = wg >> 4;
  const int b = bh >> 4, h = bh & 15;

  const u16* Q   = qkb + (size_t)bh * T_ * HD_;
  const u16* Kg  = qkb + (size_t)(32 + bh) * T_ * HD_;
  const u16* VTg = vtg + (size_t)bh * HD_ * T_;

  const int wrowB = qtB * 64 + wave * 16;
  const int wrowA = qtA * 64 + wave * 16;
  const int qB = wrowB + l15;          // this lane's S^T column (global q)
  const int qA = wrowA + l15;
  // reversed-decay base: decR[2047 - q + kt*64 + quad*4 + f*16 + r] = decay[q-key]
  const int rbase0B = 2047 - qB + quad * 4;
  const int rbase0A = 2047 - qA + quad * 4;

  bf16x8 qaB[2], qaA[2];
  { const u16* qp = Q + (size_t)(wrowB + l15) * HD_ + quad * 8;
    qaB[0] = *(const bf16x8*)qp; qaB[1] = *(const bf16x8*)(qp + 32); }
  { const u16* qp = Q + (size_t)(wrowA + l15) * HD_ + quad * 8;
    qaA[0] = *(const bf16x8*)qp; qaA[1] = *(const bf16x8*)(qp + 32); }

  f32x4 accB[4] = {}, accA[4] = {};
  float lsumB = 0.0f, lsumA = 0.0f;

#define ASTAGE(buf, kt)                                                          \
  {                                                                              \
    _Pragma("unroll")                                                            \
    for (int c = 0; c < 2; ++c) {                                                \
      int chunk = wave * 2048 + c * 1024;                                        \
      int row = (chunk >> 7) + (lane >> 3);                                      \
      int wb = ((lane & 7) << 4) ^ ((row & 7) << 4);                             \
      GLD16((const char*)(Kg + (size_t)((kt) * 64 + row) * HD_) + wb,            \
            klds[buf] + chunk);                                                  \
      GLD16((const char*)(VTg + (size_t)row * T_ + (kt) * 64) + wb,              \
            vlds[buf] + chunk);                                                  \
    }                                                                            \
  }

  ASTAGE(0, 0);
  __syncthreads();

  const int nkt = qtB + 1;
  for (int kt = 0; kt < nkt; ++kt) {
    const int cur = kt & 1;
    if (kt + 1 < nkt) ASTAGE(cur ^ 1, kt + 1);
    const bool actA = (kt <= qtA);

    // K fragments (read once, shared by both q-tiles)
    bf16x8 kf[4][2];
#pragma unroll
    for (int f = 0; f < 4; ++f) {
      int krow = f * 16 + l15;
      int base = krow * 128;
      int msk = (krow & 7) << 4;
      kf[f][0] = *(const bf16x8*)(klds[cur] + base + ((quad * 16) ^ msk));
      kf[f][1] = *(const bf16x8*)(klds[cur] + base + ((64 + quad * 16) ^ msk));
    }

    // decay factors: one unaligned dwordx4 per f-block (L1-resident table)
    const float* dRB = decR + (rbase0B + kt * 64);
    const float* dRA = decR + (rbase0A + kt * 64);
    f32x4 dB[4], dA[4];
#pragma unroll
    for (int f = 0; f < 4; ++f) dB[f] = *(const f32x4u*)(dRB + f * 16);
    if (actA) {
#pragma unroll
      for (int f = 0; f < 4; ++f) dA[f] = *(const f32x4u*)(dRA + f * 16);
    }

    // S^T = K Q^T (log2 domain): col=q=l15, row=key=f*16+quad*4+r
    f32x4 sB[4], sA[4];
    __builtin_amdgcn_s_setprio(1);
#pragma unroll
    for (int f = 0; f < 4; ++f) {
      f32x4 t = {};
      t = __builtin_amdgcn_mfma_f32_16x16x32_bf16(kf[f][0], qaB[0], t, 0, 0, 0);
      t = __builtin_amdgcn_mfma_f32_16x16x32_bf16(kf[f][1], qaB[1], t, 0, 0, 0);
      sB[f] = t;
    }
    if (actA) {
#pragma unroll
      for (int f = 0; f < 4; ++f) {
        f32x4 t = {};
        t = __builtin_amdgcn_mfma_f32_16x16x32_bf16(kf[f][0], qaA[0], t, 0, 0, 0);
        t = __builtin_amdgcn_mfma_f32_16x16x32_bf16(kf[f][1], qaA[1], t, 0, 0, 0);
        sA[f] = t;
      }
    }
    __builtin_amdgcn_s_setprio(0);

    if (kt == qtB) {   // diagonal: mask key > q
#pragma unroll
      for (int f = 0; f < 4; ++f) {
        int key0 = kt * 64 + f * 16 + quad * 4;
#pragma unroll
        for (int r = 0; r < 4; ++r)
          if (key0 + r > qB) sB[f][r] = -1e30f;
      }
    }
    if (actA && kt == qtA) {
#pragma unroll
      for (int f = 0; f < 4; ++f) {
        int key0 = kt * 64 + f * 16 + quad * 4;
#pragma unroll
        for (int r = 0; r < 4; ++r)
          if (key0 + r > qA) sA[f][r] = -1e30f;
      }
    }

    // softmax: denom = sum exp2(s); numerator = exp2(s)*decay -> packed bf16
#pragma unroll
    for (int f = 0; f < 4; ++f) {
      f32x4 p;
#pragma unroll
      for (int r = 0; r < 4; ++r) p[r] = EXP2(sB[f][r]);
      lsumB += (p[0] + p[1]) + (p[2] + p[3]);
      unsigned int w0 = cvt_pk_bf16(p[0] * dB[f][0], p[1] * dB[f][1]);
      unsigned int w1 = cvt_pk_bf16(p[2] * dB[f][2], p[3] * dB[f][3]);
      uint2 wv; wv.x = w0; wv.y = w1;
      *(uint2*)(plds + (size_t)(wave * 16 + l15) * 76 + f * 16 + quad * 4) = wv;
    }
    if (actA) {
#pragma unroll
      for (int f = 0; f < 4; ++f) {
        f32x4 p;
#pragma unroll
        for (int r = 0; r < 4; ++r) p[r] = EXP2(sA[f][r]);
        lsumA += (p[0] + p[1]) + (p[2] + p[3]);
        unsigned int w0 = cvt_pk_bf16(p[0] * dA[f][0], p[1] * dA[f][1]);
        unsigned int w1 = cvt_pk_bf16(p[2] * dA[f][2], p[3] * dA[f][3]);
        uint2 wv; wv.x = w0; wv.y = w1;
        *(uint2*)(plds + (size_t)(64 + wave * 16 + l15) * 76 + f * 16 + quad * 4) = wv;
      }
    }

    // V fragments (read once, shared)
    bf16x8 vf[4][2];
#pragma unroll
    for (int n = 0; n < 4; ++n) {
      int vrow = n * 16 + l15;
      int mskv = (vrow & 7) << 4;
#pragma unroll
      for (int ks = 0; ks < 2; ++ks)
        vf[n][ks] = *(const bf16x8*)(vlds[cur] + vrow * 128 + ((ks * 64 + quad * 16) ^ mskv));
    }

    // y += P @ V
    __builtin_amdgcn_s_setprio(1);
#pragma unroll
    for (int ks = 0; ks < 2; ++ks) {
      bf16x8 pa = *(const bf16x8*)(plds + (size_t)(wave * 16 + l15) * 76 + ks * 32 + quad * 8);
#pragma unroll
      for (int n = 0; n < 4; ++n)
        accB[n] = __builtin_amdgcn_mfma_f32_16x16x32_bf16(pa, vf[n][ks], accB[n], 0, 0, 0);
    }
    if (actA) {
#pragma unroll
      for (int ks = 0; ks < 2; ++ks) {
        bf16x8 pa = *(const bf16x8*)(plds + (size_t)(64 + wave * 16 + l15) * 76 + ks * 32 + quad * 8);
#pragma unroll
        for (int n = 0; n < 4; ++n)
          accA[n] = __builtin_amdgcn_mfma_f32_16x16x32_bf16(pa, vf[n][ks], accA[n], 0, 0, 0);
      }
    }
    __builtin_amdgcn_s_setprio(0);
    __syncthreads();   // drains vmcnt(0): next buffer staged, everyone done with cur
  }
#undef ASTAGE

  // finalize: denom for q=l15 -> reduce across quads, broadcast to q=quad*4+r
  lsumB += __shfl_xor(lsumB, 16); lsumB += __shfl_xor(lsumB, 32);
  lsumA += __shfl_xor(lsumA, 16); lsumA += __shfl_xor(lsumA, 32);
  float rB[4], rA[4];
#pragma unroll
  for (int r = 0; r < 4; ++r) {
    rB[r] = 1.0f / __shfl(lsumB, quad * 4 + r, 16);
    rA[r] = 1.0f / __shfl(lsumA, quad * 4 + r, 16);
  }
#pragma unroll
  for (int n = 0; n < 4; ++n) {
    int d = h * 64 + n * 16 + l15;
#pragma unroll
    for (int r = 0; r < 4; ++r) {
      int tB = wrowB + quad * 4 + r;
      int tA = wrowA + quad * 4 + r;
      yb[((size_t)b * T_ + tB) * 1024 + d] = f2bf(accB[n][r] * rB[r]);
      yb[((size_t)b * T_ + tA) * 1024 + d] = f2bf(accA[n][r] * rA[r]);
    }
  }
}

// ---------------- launch ----------------
extern "C" void kernel_launch(void* const* d_in, const int* in_sizes, int n_in,
                              void* d_out, int out_size, void* d_ws, size_t ws_size,
                              hipStream_t stream) {
  const float* x  = (const float*)d_in[0];
  const float* Wa = (const float*)d_in[1];
  const float* Wp = (const float*)d_in[2];
  float* out = (float*)d_out;
  char* ws = (char*)d_ws;

  // workspace layout (bytes), total 50,331,648
  u16*   xb    = (u16*)(ws + 0);           //  8,388,608  x bf16; reused as yb
  u16*   WaT   = (u16*)(ws + 8388608);     //  6,291,456  W_attn^T bf16
  u16*   WpT   = (u16*)(ws + 14680064);    //  2,097,152  W_proj^T bf16
  u16*   qkb   = (u16*)(ws + 16777216);    // 16,777,216  Q,K bf16 [2][32][2048][64]
  u16*   Vtmp  = (u16*)(ws + 33554432);    //  8,388,608  V bf16 (dead after vtrans;
                                           //             head reused for decay table)
  u16*   VT    = (u16*)(ws + 41943040);    //  8,388,608  V^T bf16 [32][64][2048]
  float* decR  = (float*)Vtmp;             //  8,704 B    reversed padded decay table
  u16*   yb    = xb;

  cvt4_kernel<<<4096, 256, 0, stream>>>(x, xb, B_ * T_ * C_);
  transpose_cvt_kernel<<<dim3(96, 32), 256, 0, stream>>>(Wa, WaT, C_, N3_);
  transpose_cvt_kernel<<<dim3(32, 32), 256, 0, stream>>>(Wp, WpT, C_, C_);

  gemm128_kernel<0><<<768, 256, 0, stream>>>(
      xb, WaT, nullptr, qkb, Vtmp, B_ * T_, N3_, C_);
  vtrans_kernel<<<dim3(32, 32), 256, 0, stream>>>(Vtmp, VT);
  decay_init_kernel<<<9, 256, 0, stream>>>(decR);   // after vtrans: overwrites Vtmp head
  attn_kernel<<<512, 256, 0, stream>>>(qkb, VT, decR, yb);
  gemm128_kernel<1><<<256, 256, 0, stream>>>(
      yb, WpT, out, nullptr, nullptr, B_ * T_, 1024, 1024);
}

// Round 7
// 118.981 us; speedup vs baseline: 1.8565x; 1.0147x over previous
//
#include <hip/hip_runtime.h>
#include <math.h>

// ws footprint: 50,331,648 bytes (decay table lives in the free Vtmp region).
#define B_  2
#define T_  2048
#define C_  1024
#define NH_ 16
#define HD_ 64
#define N3_ 3072

typedef float f32x4 __attribute__((ext_vector_type(4)));
typedef short bf16x8 __attribute__((ext_vector_type(8)));
typedef unsigned short u16;
typedef float f32x4_base __attribute__((ext_vector_type(4)));
typedef f32x4_base __attribute__((aligned(4))) f32x4u;   // 4B-aligned vector load

// Q prescale: 1/sqrt(64) * log2(e), so softmax uses exp2 directly.
#define QSCALE 0.18033688011112042f

#if __has_builtin(__builtin_amdgcn_exp2f)
#define EXP2(x) __builtin_amdgcn_exp2f(x)
#else
#define EXP2(x) exp2f(x)
#endif

__device__ __forceinline__ u16 f2bf(float x) {
  unsigned int u = __builtin_bit_cast(unsigned int, x);
  u += 0x7FFFu + ((u >> 16) & 1u);
  return (u16)(u >> 16);
}

__device__ __forceinline__ unsigned int cvt_pk_bf16(float lo, float hi) {
  unsigned int r;
  asm("v_cvt_pk_bf16_f32 %0, %1, %2" : "=v"(r) : "v"(lo), "v"(hi));
  return r;
}

#define GLD16(g, l) __builtin_amdgcn_global_load_lds( \
    (__attribute__((address_space(1))) void*)(g), \
    (__attribute__((address_space(3))) void*)(l), 16, 0, 0)

// ---------------- converts ----------------
__global__ __launch_bounds__(256) void cvt4_kernel(const float* __restrict__ in,
                                                   u16* __restrict__ out, int n) {
  int i = (blockIdx.x * 256 + threadIdx.x) * 4;
  if (i >= n) return;
  float4 v = *(const float4*)(in + i);
  ushort4 o;
  o.x = f2bf(v.x); o.y = f2bf(v.y); o.z = f2bf(v.z); o.w = f2bf(v.w);
  *(ushort4*)(out + i) = o;
}

// out[c][r] = bf16(in[r][c]); R,Cc multiples of 32
__global__ __launch_bounds__(256) void transpose_cvt_kernel(const float* __restrict__ in,
                                                            u16* __restrict__ out,
                                                            int R, int Cc) {
  __shared__ float tile[32][33];
  int c0 = blockIdx.x * 32, r0 = blockIdx.y * 32;
  int tx = threadIdx.x & 31, ty = threadIdx.x >> 5;
#pragma unroll
  for (int rr = ty; rr < 32; rr += 8)
    tile[rr][tx] = in[(size_t)(r0 + rr) * Cc + c0 + tx];
  __syncthreads();
#pragma unroll
  for (int rr = ty; rr < 32; rr += 8)
    out[(size_t)(c0 + rr) * R + r0 + tx] = f2bf(tile[tx][rr]);
}

// Reversed + padded decay table: decR[j] = decay(2047-j) for j<=2047, 1.0 above
// (pad entries are only ever multiplied by p==0 in the masked region).
__global__ __launch_bounds__(256) void decay_init_kernel(float* __restrict__ decR) {
  int j = blockIdx.x * 256 + threadIdx.x;
  if (j >= 2176) return;
  int d = 2047 - j;
  float v = 1.0f;
  if (d >= 15) v = 1.0f - powf((float)(d - 15) * (1.0f / 2032.0f), 0.36787944117144233f);
  decR[j] = v;   // d < 15 (incl. negative pad) -> 1.0
}

// ---------------- GEMM: C[M][N] = A[M][K] * Bt[N][K]^T ----------------
// 128x128 tile, 4 waves, BK=32, double-buffered LDS, 1 barrier/iter.
// Flattened grid with bijective XCD-chunk swizzle (grid %8 == 0).
// MODE 0: Q,K bf16 into qkb [which][bh][t][d] (Q prescaled);
//         V written TRANSPOSED into VT [bh][d][t] (ushort4 over 4 consecutive t).
// MODE 1: fp32 row-major.
template<int MODE>
__global__ __launch_bounds__(256, 3) void gemm128_kernel(
    const u16* __restrict__ A, const u16* __restrict__ Bt,
    float* __restrict__ Cf, u16* __restrict__ Cq, u16* __restrict__ Vt,
    int M, int N, int K)
{
  __shared__ char lds[32768];
  const int lane = threadIdx.x & 63;
  const int wave = threadIdx.x >> 6;
  const int nxb = N >> 7;
  const int orig = blockIdx.x;
  const int cpx = (int)gridDim.x >> 3;
  const int wg = (orig & 7) * cpx + (orig >> 3);
  const int m0 = (wg / nxb) << 7;
  const int n0 = (wg % nxb) << 7;
  const int wm = wave >> 1, wn = wave & 1;

  f32x4 acc[4][4] = {};

#define GSTAGE(buf, k0)                                                          \
  {                                                                              \
    _Pragma("unroll")                                                            \
    for (int c = 0; c < 2; ++c) {                                                \
      int chunk = wave * 2048 + c * 1024;                                        \
      int row = (chunk >> 6) + (lane >> 2);                                      \
      int wb = ((lane & 3) << 4) ^ ((row & 3) << 4);                             \
      GLD16((const char*)(A  + (size_t)(m0 + row) * K + (k0)) + wb,              \
            lds + (buf) * 16384 + chunk);                                        \
      GLD16((const char*)(Bt + (size_t)(n0 + row) * K + (k0)) + wb,              \
            lds + (buf) * 16384 + 8192 + chunk);                                 \
    }                                                                            \
  }

  GSTAGE(0, 0);
  __syncthreads();

  for (int k0 = 0; k0 < K; k0 += 32) {
    const int cur = (k0 >> 5) & 1;
    if (k0 + 32 < K) GSTAGE(cur ^ 1, k0 + 32);
    const char* base = lds + cur * 16384;
    bf16x8 af[4], bfr[4];
#pragma unroll
    for (int m = 0; m < 4; ++m) {
      int row = wm * 64 + m * 16 + (lane & 15);
      int wb = ((lane >> 4) << 4) ^ ((row & 3) << 4);
      af[m] = *(const bf16x8*)(base + row * 64 + wb);
    }
#pragma unroll
    for (int n = 0; n < 4; ++n) {
      int row = wn * 64 + n * 16 + (lane & 15);
      int wb = ((lane >> 4) << 4) ^ ((row & 3) << 4);
      bfr[n] = *(const bf16x8*)(base + 8192 + row * 64 + wb);
    }
    __builtin_amdgcn_s_setprio(1);
#pragma unroll
    for (int m = 0; m < 4; ++m)
#pragma unroll
      for (int n = 0; n < 4; ++n)
        acc[m][n] = __builtin_amdgcn_mfma_f32_16x16x32_bf16(af[m], bfr[n], acc[m][n], 0, 0, 0);
    __builtin_amdgcn_s_setprio(0);
    __syncthreads();
  }

#pragma unroll
  for (int m = 0; m < 4; ++m) {
    int grow0 = m0 + wm * 64 + m * 16 + ((lane >> 4) << 2);
#pragma unroll
    for (int n = 0; n < 4; ++n) {
      int gcol = n0 + wn * 64 + n * 16 + (lane & 15);
      f32x4 v = acc[m][n];
      if (MODE == 0) {
        int bb = grow0 >> 11, tt0 = grow0 & 2047;
        int which = gcol >> 10, rem = gcol & 1023;
        int hh = rem >> 6, dd = rem & 63;
        if (which < 2) {
#pragma unroll
          for (int r = 0; r < 4; ++r) {
            float ov = (which == 0) ? v[r] * QSCALE : v[r];
            Cq[((size_t)(which * 32 + bb * 16 + hh) * 2048 + tt0 + r) * 64 + dd] = f2bf(ov);
          }
        } else {
          ushort4 o;
          o.x = f2bf(v[0]); o.y = f2bf(v[1]); o.z = f2bf(v[2]); o.w = f2bf(v[3]);
          *(ushort4*)(Vt + ((size_t)(bb * 16 + hh) * 64 + dd) * 2048 + tt0) = o;
        }
      } else {
#pragma unroll
        for (int r = 0; r < 4; ++r)
          Cf[(size_t)(grow0 + r) * N + gcol] = v[r];
      }
    }
  }
#undef GSTAGE
}

// ---------------- fused flash attention with post-softmax decay ----------------
// flat grid 1024, one 64-row q-tile per block; 4 waves x 16 rows; LDS 40960 ->
// 4 blocks/CU (16 waves/CU). qt chosen so the 4 stride-(grid/4) CU-mates get
// qt = {a, 15-a, 16+a, 31-a}: per-CU work constant (66 iters), same bh (L2).
// S^T = mfma(K,Q): col=q=lane&15, row=key=quad*4+r -> keys lane-local.
__global__ __launch_bounds__(256, 4) void attn_kernel(
    const u16* __restrict__ qkb, const u16* __restrict__ vtg,
    const float* __restrict__ decR, u16* __restrict__ yb)
{
  __shared__ char klds[2][8192];   // K tile [64 keys][128B], XOR-swizzled
  __shared__ char vlds[2][8192];   // V^T tile [64 d][128B keys], XOR-swizzled
  __shared__ char plds[8192];      // P [64 q][64 keys] bf16, XOR-swizzled rows

  const int lane = threadIdx.x & 63;
  const int wave = threadIdx.x >> 6;
  const int quad = lane >> 4;
  const int l15 = lane & 15;
  const int orig = blockIdx.x;
  const int sub = ((orig & 7) << 7) + (orig >> 3);   // 128 blocks per XCD
  const int a = sub & 7;
  const int bh = ((orig & 7) << 2) + ((sub >> 3) & 3);
  const int k4 = (sub >> 5) & 3;
  const int qt = k4 * 8 + ((k4 & 1) ? (7 - a) : a);
  const int b = bh >> 4, h = bh & 15;

  const u16* Q   = qkb + (size_t)bh * T_ * HD_;
  const u16* Kg  = qkb + (size_t)(32 + bh) * T_ * HD_;
  const u16* VTg = vtg + (size_t)bh * HD_ * T_;

  const int wrow = qt * 64 + wave * 16;
  const int q = wrow + l15;            // this lane's S^T column (global q)
  const int rbase0 = 2047 - q + quad * 4;
  const int prow = wave * 16 + l15;    // plds row (this lane's q, local)
  const int pswz = (l15 & 7) << 4;

  bf16x8 qa[2];
  { const u16* qp = Q + (size_t)q * HD_ + quad * 8;
    qa[0] = *(const bf16x8*)qp; qa[1] = *(const bf16x8*)(qp + 32); }

  f32x4 acc[4] = {};
  float lsum = 0.0f;

#define ASTAGE(buf, kt)                                                          \
  {                                                                              \
    _Pragma("unroll")                                                            \
    for (int c = 0; c < 2; ++c) {                                                \
      int chunk = wave * 2048 + c * 1024;                                        \
      int row = (chunk >> 7) + (lane >> 3);                                      \
      int wb = ((lane & 7) << 4) ^ ((row & 7) << 4);                             \
      GLD16((const char*)(Kg + (size_t)((kt) * 64 + row) * HD_) + wb,            \
            klds[buf] + chunk);                                                  \
      GLD16((const char*)(VTg + (size_t)row * T_ + (kt) * 64) + wb,              \
            vlds[buf] + chunk);                                                  \
    }                                                                            \
  }

  ASTAGE(0, 0);
  __syncthreads();

  const int nkt = qt + 1;
  for (int kt = 0; kt < nkt; ++kt) {
    const int cur = kt & 1;
    if (kt + 1 < nkt) ASTAGE(cur ^ 1, kt + 1);

    // K fragments
    bf16x8 kf[4][2];
#pragma unroll
    for (int f = 0; f < 4; ++f) {
      int krow = f * 16 + l15;
      int base = krow * 128;
      int msk = (krow & 7) << 4;
      kf[f][0] = *(const bf16x8*)(klds[cur] + base + ((quad * 16) ^ msk));
      kf[f][1] = *(const bf16x8*)(klds[cur] + base + ((64 + quad * 16) ^ msk));
    }

    // decay factors: one dwordx4 per f-block from the reversed table (L1-hot)
    const float* dR = decR + (rbase0 + kt * 64);
    f32x4 dB[4];
#pragma unroll
    for (int f = 0; f < 4; ++f) dB[f] = *(const f32x4u*)(dR + f * 16);

    // S^T = K Q^T (log2 domain): col=q=l15, row=key=f*16+quad*4+r
    f32x4 s[4];
    __builtin_amdgcn_s_setprio(1);
#pragma unroll
    for (int f = 0; f < 4; ++f) {
      f32x4 t = {};
      t = __builtin_amdgcn_mfma_f32_16x16x32_bf16(kf[f][0], qa[0], t, 0, 0, 0);
      t = __builtin_amdgcn_mfma_f32_16x16x32_bf16(kf[f][1], qa[1], t, 0, 0, 0);
      s[f] = t;
    }
    __builtin_amdgcn_s_setprio(0);

    if (kt == qt) {   // diagonal: mask key > q
#pragma unroll
      for (int f = 0; f < 4; ++f) {
        int key0 = kt * 64 + f * 16 + quad * 4;
#pragma unroll
        for (int r = 0; r < 4; ++r)
          if (key0 + r > q) s[f][r] = -1e30f;
      }
    }

    // softmax: denom = sum exp2(s); numerator = exp2(s)*decay -> packed bf16
#pragma unroll
    for (int f = 0; f < 4; ++f) {
      f32x4 p;
#pragma unroll
      for (int r = 0; r < 4; ++r) p[r] = EXP2(s[f][r]);
      lsum += (p[0] + p[1]) + (p[2] + p[3]);
      unsigned int w0 = cvt_pk_bf16(p[0] * dB[f][0], p[1] * dB[f][1]);
      unsigned int w1 = cvt_pk_bf16(p[2] * dB[f][2], p[3] * dB[f][3]);
      uint2 wv; wv.x = w0; wv.y = w1;
      *(uint2*)(plds + prow * 128 + ((f * 32 + quad * 8) ^ pswz)) = wv;
    }

    // V fragments
    bf16x8 vf[4][2];
#pragma unroll
    for (int n = 0; n < 4; ++n) {
      int vrow = n * 16 + l15;
      int mskv = (vrow & 7) << 4;
#pragma unroll
      for (int ks = 0; ks < 2; ++ks)
        vf[n][ks] = *(const bf16x8*)(vlds[cur] + vrow * 128 + ((ks * 64 + quad * 16) ^ mskv));
    }

    // y += P @ V (plds rows are wave-private; same-wave ds order suffices)
    __builtin_amdgcn_s_setprio(1);
#pragma unroll
    for (int ks = 0; ks < 2; ++ks) {
      bf16x8 pa = *(const bf16x8*)(plds + prow * 128 + ((ks * 64 + quad * 16) ^ pswz));
#pragma unroll
      for (int n = 0; n < 4; ++n)
        acc[n] = __builtin_amdgcn_mfma_f32_16x16x32_bf16(pa, vf[n][ks], acc[n], 0, 0, 0);
    }
    __builtin_amdgcn_s_setprio(0);
    __syncthreads();   // drains vmcnt(0): next buffer staged, everyone done with cur
  }
#undef ASTAGE

  // finalize: denom for q=l15 -> reduce across quads, broadcast to q=quad*4+r
  lsum += __shfl_xor(lsum, 16); lsum += __shfl_xor(lsum, 32);
  float rb[4];
#pragma unroll
  for (int r = 0; r < 4; ++r)
    rb[r] = 1.0f / __shfl(lsum, quad * 4 + r, 16);
#pragma unroll
  for (int n = 0; n < 4; ++n) {
    int d = h * 64 + n * 16 + l15;
#pragma unroll
    for (int r = 0; r < 4; ++r) {
      int t = wrow + quad * 4 + r;
      yb[((size_t)b * T_ + t) * 1024 + d] = f2bf(acc[n][r] * rb[r]);
    }
  }
}

// ---------------- launch ----------------
extern "C" void kernel_launch(void* const* d_in, const int* in_sizes, int n_in,
                              void* d_out, int out_size, void* d_ws, size_t ws_size,
                              hipStream_t stream) {
  const float* x  = (const float*)d_in[0];
  const float* Wa = (const float*)d_in[1];
  const float* Wp = (const float*)d_in[2];
  float* out = (float*)d_out;
  char* ws = (char*)d_ws;

  // workspace layout (bytes), total 50,331,648
  u16*   xb    = (u16*)(ws + 0);           //  8,388,608  x bf16; reused as yb
  u16*   WaT   = (u16*)(ws + 8388608);     //  6,291,456  W_attn^T bf16
  u16*   WpT   = (u16*)(ws + 14680064);    //  2,097,152  W_proj^T bf16
  u16*   qkb   = (u16*)(ws + 16777216);    // 16,777,216  Q,K bf16 [2][32][2048][64]
  float* decR  = (float*)(ws + 33554432);  //      8,704  reversed padded decay table
  u16*   VT    = (u16*)(ws + 41943040);    //  8,388,608  V^T bf16 [32][64][2048]
  u16*   yb    = xb;

  decay_init_kernel<<<9, 256, 0, stream>>>(decR);
  cvt4_kernel<<<4096, 256, 0, stream>>>(x, xb, B_ * T_ * C_);
  transpose_cvt_kernel<<<dim3(96, 32), 256, 0, stream>>>(Wa, WaT, C_, N3_);
  transpose_cvt_kernel<<<dim3(32, 32), 256, 0, stream>>>(Wp, WpT, C_, C_);

  gemm128_kernel<0><<<768, 256, 0, stream>>>(
      xb, WaT, nullptr, qkb, VT, B_ * T_, N3_, C_);
  attn_kernel<<<1024, 256, 0, stream>>>(qkb, VT, decR, yb);
  gemm128_kernel<1><<<256, 256, 0, stream>>>(
      yb, WpT, out, nullptr, nullptr, B_ * T_, 1024, 1024);
}